// Round 4
// baseline (1124.601 us; speedup 1.0000x reference)
//
#include <hip/hip_runtime.h>
#include <hip/hip_bf16.h>
#include <math.h>

#define MORD 862

typedef short s16x8 __attribute__((ext_vector_type(8)));
typedef float f32x4 __attribute__((ext_vector_type(4)));

static __device__ __forceinline__ unsigned short f2bf(float v) {
  __hip_bfloat16 h = __float2bfloat16(v);
  return *(unsigned short*)&h;
}

__global__ __launch_bounds__(256) void deg_kernel(const int* __restrict__ dst, int* __restrict__ deg, int E) {
  int e = blockIdx.x * blockDim.x + threadIdx.x;
  if (e < E) atomicAdd(&deg[dst[e]], 1);
}

// ---- CSR build: 2-level exclusive scan of deg ----
__global__ __launch_bounds__(256) void scan_block(const int* __restrict__ deg, int* __restrict__ bsum, int N) {
  __shared__ int ts[256];
  int base = blockIdx.x * 1024 + threadIdx.x * 4;
  int s = 0;
#pragma unroll
  for (int j = 0; j < 4; j++) {
    int i = base + j;
    if (i < N) s += deg[i];
  }
  ts[threadIdx.x] = s;
  __syncthreads();
  for (int st = 128; st > 0; st >>= 1) {
    if (threadIdx.x < st) ts[threadIdx.x] += ts[threadIdx.x + st];
    __syncthreads();
  }
  if (threadIdx.x == 0) bsum[blockIdx.x] = ts[0];
}

__global__ __launch_bounds__(1024) void scan_bsum(int* __restrict__ bsum, int nb) {
  __shared__ int ts[1024];
  int tid = threadIdx.x;
  int v = (tid < nb) ? bsum[tid] : 0;
  ts[tid] = v;
  __syncthreads();
  for (int st = 1; st < 1024; st <<= 1) {
    int t = (tid >= st) ? ts[tid - st] : 0;
    __syncthreads();
    ts[tid] += t;
    __syncthreads();
  }
  if (tid < nb) bsum[tid] = ts[tid] - v;  // exclusive
}

__global__ __launch_bounds__(256) void scan_write(const int* __restrict__ deg, const int* __restrict__ bsum,
                                                  int* __restrict__ off, int* __restrict__ cursor, int N, int E) {
  __shared__ int ts[256];
  int tid = threadIdx.x;
  int base = blockIdx.x * 1024 + tid * 4;
  int v[4];
  int s = 0;
#pragma unroll
  for (int j = 0; j < 4; j++) {
    int i = base + j;
    v[j] = (i < N) ? deg[i] : 0;
    s += v[j];
  }
  int own = s;
  ts[tid] = s;
  __syncthreads();
  for (int st = 1; st < 256; st <<= 1) {
    int t = (tid >= st) ? ts[tid - st] : 0;
    __syncthreads();
    ts[tid] += t;
    __syncthreads();
  }
  int pre = ts[tid] - own + bsum[blockIdx.x];
#pragma unroll
  for (int j = 0; j < 4; j++) {
    int i = base + j;
    if (i < N) {
      off[i] = pre;
      cursor[i] = pre;
      pre += v[j];
    }
  }
  if (blockIdx.x == 0 && tid == 0) off[N] = E;
}

__global__ __launch_bounds__(256) void csr_fill(const int* __restrict__ src, const int* __restrict__ dst,
                                                int* __restrict__ cursor, int* __restrict__ csr, int E) {
  int e = blockIdx.x * blockDim.x + threadIdx.x;
  if (e < E) {
    int p = atomicAdd(&cursor[dst[e]], 1);
    csr[p] = src[e];
  }
}

// graph segment starts: goff[b] = lower_bound(batch, b), b in [0,B]
__global__ __launch_bounds__(256) void graph_off(const int* __restrict__ batch, int* __restrict__ goff, int N, int B) {
  int b = blockIdx.x * blockDim.x + threadIdx.x;
  if (b > B) return;
  int lo = 0, hi = N;
  while (lo < hi) {
    int mid = (lo + hi) >> 1;
    if (batch[mid] < b) lo = mid + 1; else hi = mid;
  }
  goff[b] = lo;
}

// Fused gather(sum over CSR neighbors) + degree-conditioned transform. LDS weights [d][i][o].
template <int CIN, bool RELU>
__global__ __launch_bounds__(512) void mfconv_fused(const float* __restrict__ xin,
                                                    const int* __restrict__ off, const int* __restrict__ csr,
                                                    const float* __restrict__ Wl, const float* __restrict__ bl,
                                                    const float* __restrict__ Wr,
                                                    float* __restrict__ out, int N) {
  __shared__ float swl[11 * CIN * 32];
  __shared__ float swr[11 * CIN * 32];
  __shared__ float sbl[11 * 32];
  __shared__ float sh[16 * CIN];
  __shared__ float sx[16 * CIN];

  for (int idx = threadIdx.x; idx < 11 * CIN * 32; idx += 512) {
    int d = idx / (CIN * 32);
    int i = (idx >> 5) % CIN;
    int o = idx & 31;
    swl[idx] = Wl[((size_t)d * 32 + o) * CIN + i];
    swr[idx] = Wr[((size_t)d * 32 + o) * CIN + i];
  }
  for (int idx = threadIdx.x; idx < 11 * 32; idx += 512) sbl[idx] = bl[idx];

  int o = threadIdx.x & 31, ns = threadIdx.x >> 5;

  for (long long n0 = (long long)blockIdx.x * 16; n0 < N; n0 += (long long)gridDim.x * 16) {
    __syncthreads();
    for (int idx = threadIdx.x; idx < 16 * CIN; idx += 512) {
      int nn = idx / CIN, i = idx % CIN;
      long long n = n0 + nn;
      if (n < N) {
        int a = off[n], b2 = off[n + 1];
        float s = 0.f;
        for (int j = a; j < b2; j++) s += xin[(size_t)csr[j] * CIN + i];
        sh[nn * CIN + i] = s;
        sx[nn * CIN + i] = xin[n * CIN + i];
      }
    }
    __syncthreads();
    long long n = n0 + ns;
    if (n < N) {
      int dg = off[n + 1] - off[n];
      int d = dg < 10 ? dg : 10;
      int wb = d * CIN * 32 + o;
      float acc = sbl[d * 32 + o];
#pragma unroll
      for (int i = 0; i < CIN; i++)
        acc = fmaf(swl[wb + i * 32], sh[ns * CIN + i], fmaf(swr[wb + i * 32], sx[ns * CIN + i], acc));
      if (RELU) acc = fmaxf(acc, 0.f);
      out[n * 32 + o] = acc;
    }
  }
}

// one wave per graph; writes mean directly (no atomics)
__global__ __launch_bounds__(256) void pool_seg(const float* __restrict__ h, const int* __restrict__ goff,
                                                float* __restrict__ pooled, int B) {
  int w = (int)((blockIdx.x * 256 + threadIdx.x) >> 6);
  if (w >= B) return;
  int lane = threadIdx.x & 63;
  int c = lane & 31, r2 = lane >> 5;
  int a = goff[w], b = goff[w + 1];
  float s = 0.f;
  for (int r = a + r2; r < b; r += 2) s += h[(size_t)r * 32 + c];
  s += __shfl_down(s, 32);
  if (r2 == 0) pooled[(size_t)w * 32 + c] = s / fmaxf((float)(b - a), 1.f);
}

// fp32 -> bf16 with K padding to Kp (zeros in pad)
__global__ __launch_bounds__(256) void cvt_bf16_pad(const float* __restrict__ src, unsigned short* __restrict__ dst,
                                                    int rows, int K, int Kp) {
  int t = blockIdx.x * blockDim.x + threadIdx.x;
  int q = Kp / 4;
  if (t >= rows * q) return;
  int r = t / q, c4 = (t % q) * 4;
#pragma unroll
  for (int j = 0; j < 4; j++) {
    int k = c4 + j;
    float v = (k < K) ? src[(size_t)r * K + k] : 0.f;
    dst[(size_t)r * Kp + k] = f2bf(v);
  }
}

__global__ __launch_bounds__(256) void prepW2_kernel(const float* __restrict__ W2, const float* __restrict__ b2,
                                                     const float* __restrict__ a1, const float* __restrict__ h1,
                                                     unsigned short* __restrict__ W2p, float* __restrict__ b2p,
                                                     int Nn, int K) {
  int wid = threadIdx.x >> 6, lane = threadIdx.x & 63;
  int n = blockIdx.x * 4 + wid;
  if (n >= Nn) return;
  float part = 0.f;
  for (int k = lane; k < K; k += 64) {
    float w = W2[(size_t)n * K + k];
    W2p[(size_t)n * K + k] = f2bf(w * a1[k]);
    part = fmaf(w, h1[k], part);
  }
#pragma unroll
  for (int off = 32; off > 0; off >>= 1) part += __shfl_down(part, off, 64);
  if (lane == 0) b2p[n] = b2[n] + part;
}

// bf16 MFMA GEMM: C[M,Nn] = relu(A[M,Kp] @ Bw[Nn,Kp]^T + bias). 128x128 tile, BK=64.
template <int OUTBF16>
__global__ __launch_bounds__(256) void gemm_mfma(const unsigned short* __restrict__ A,
                                                 const unsigned short* __restrict__ Bw,
                                                 const float* __restrict__ bias,
                                                 void* __restrict__ Cout, int M, int Nn, int Kp) {
  __shared__ unsigned short As[128 * 64];
  __shared__ unsigned short Bs[128 * 64];
  int tid = threadIdx.x;
  int wid = tid >> 6, lane = tid & 63;
  int m0 = blockIdx.y * 128, n0 = blockIdx.x * 128;
  int wr = wid >> 1, wc = wid & 1;
  f32x4 acc[4][4] = {};

  int srow_l = lane >> 3;
  int scol = (lane & 7) * 8;
  int aReadBase = ((wr * 64 + (lane & 15)) * 128) + ((lane >> 4) * 16);
  int bReadBase = ((wc * 64 + (lane & 15)) * 128) + ((lane >> 4) * 16);

  const unsigned short* Ablk = A + (size_t)m0 * Kp;
  const unsigned short* Bblk = Bw + (size_t)n0 * Kp;

  for (int k0 = 0; k0 < Kp; k0 += 64) {
#pragma unroll
    for (int i = 0; i < 4; i++) {
      int s = wid * 4 + i;
      int row = s * 8 + srow_l;
      const unsigned short* ga = Ablk + (size_t)row * Kp + k0 + scol;
      const unsigned short* gb = Bblk + (size_t)row * Kp + k0 + scol;
      __builtin_amdgcn_global_load_lds((const __attribute__((address_space(1))) void*)ga,
                                       (__attribute__((address_space(3))) void*)(As + s * 512), 16, 0, 0);
      __builtin_amdgcn_global_load_lds((const __attribute__((address_space(1))) void*)gb,
                                       (__attribute__((address_space(3))) void*)(Bs + s * 512), 16, 0, 0);
    }
    __syncthreads();
#pragma unroll
    for (int kk = 0; kk < 2; kk++) {
      s16x8 af[4], bfr[4];
#pragma unroll
      for (int m = 0; m < 4; m++)
        af[m] = *(const s16x8*)((const char*)As + aReadBase + m * (16 * 128) + kk * 64);
#pragma unroll
      for (int n = 0; n < 4; n++)
        bfr[n] = *(const s16x8*)((const char*)Bs + bReadBase + n * (16 * 128) + kk * 64);
#pragma unroll
      for (int m = 0; m < 4; m++)
#pragma unroll
        for (int n = 0; n < 4; n++)
          acc[m][n] = __builtin_amdgcn_mfma_f32_16x16x32_bf16(af[m], bfr[n], acc[m][n], 0, 0, 0);
    }
    __syncthreads();
  }

  int rbase = m0 + wr * 64 + (lane >> 4) * 4;
  int cbase = n0 + wc * 64 + (lane & 15);
#pragma unroll
  for (int m = 0; m < 4; m++)
#pragma unroll
    for (int n = 0; n < 4; n++) {
      int col = cbase + n * 16;
      float bv = bias[col];
#pragma unroll
      for (int j = 0; j < 4; j++) {
        int row = rbase + m * 16 + j;
        float v = fmaxf(acc[m][n][j] + bv, 0.f);
        if (OUTBF16)
          ((unsigned short*)Cout)[(size_t)row * Nn + col] = f2bf(v);
        else
          ((float*)Cout)[(size_t)row * Nn + col] = v;
      }
    }
}

// fp32 fallback GEMM (used for fc3)
template <bool RELU>
__global__ __launch_bounds__(256) void gemm_bias(const float* __restrict__ A, const float* __restrict__ Bw,
                                                 const float* __restrict__ bias,
                                                 const float* __restrict__ scA, const float* __restrict__ shA,
                                                 float* __restrict__ C, int M, int Nn, int K) {
  const int BM = 64, BN = 64, BK = 16;
  __shared__ float As[BK][BM + 1];
  __shared__ float Bs[BK][BN + 1];
  int bm = blockIdx.y * BM, bn = blockIdx.x * BN;
  int tid = threadIdx.x;
  int tr = tid / 16, tc = tid % 16;
  float acc[4][4] = {};
  for (int k0 = 0; k0 < K; k0 += BK) {
    for (int i = tid; i < BM * BK; i += 256) {
      int m = i / BK, k = i % BK;
      float v = 0.f;
      if (k0 + k < K) {
        v = A[(size_t)(bm + m) * K + k0 + k];
        if (scA) v = fmaf(v, scA[k0 + k], shA[k0 + k]);
      }
      As[k][m] = v;
    }
    for (int i = tid; i < BN * BK; i += 256) {
      int n = i / BK, k = i % BK;
      float v = 0.f;
      if (k0 + k < K) v = Bw[(size_t)(bn + n) * K + k0 + k];
      Bs[k][n] = v;
    }
    __syncthreads();
#pragma unroll
    for (int k = 0; k < BK; k++) {
      float a4[4], b4[4];
#pragma unroll
      for (int xx = 0; xx < 4; xx++) a4[xx] = As[k][tr * 4 + xx];
#pragma unroll
      for (int yy = 0; yy < 4; yy++) b4[yy] = Bs[k][tc * 4 + yy];
#pragma unroll
      for (int xx = 0; xx < 4; xx++)
#pragma unroll
        for (int yy = 0; yy < 4; yy++) acc[xx][yy] = fmaf(a4[xx], b4[yy], acc[xx][yy]);
    }
    __syncthreads();
  }
  for (int xx = 0; xx < 4; xx++) {
    int m = bm + tr * 4 + xx;
    for (int yy = 0; yy < 4; yy++) {
      int n = bn + tc * 4 + yy;
      float v = acc[xx][yy] + bias[n];
      if (RELU) v = fmaxf(v, 0.f);
      C[(size_t)m * Nn + n] = v;
    }
  }
}

__global__ __launch_bounds__(256) void colstats_kernel(const float* __restrict__ X, int M, int C,
                                                       float* __restrict__ sum, float* __restrict__ sumsq) {
  int cl = threadIdx.x & 63, rl = threadIdx.x >> 6;
  int c = blockIdx.x * 64 + cl;
  float s = 0.f, q = 0.f;
  int r0 = blockIdx.y * 256;
  int rend = min(r0 + 256, M);
  for (int r = r0 + rl; r < rend; r += 4) {
    float v = X[(size_t)r * C + c];
    s += v;
    q = fmaf(v, v, q);
  }
  __shared__ float ss[4][64];
  __shared__ float qq[4][64];
  ss[rl][cl] = s;
  qq[rl][cl] = q;
  __syncthreads();
  if (rl == 0) {
    s = ss[0][cl] + ss[1][cl] + ss[2][cl] + ss[3][cl];
    q = qq[0][cl] + qq[1][cl] + qq[2][cl] + qq[3][cl];
    atomicAdd(&sum[c], s);
    atomicAdd(&sumsq[c], q);
  }
}

__global__ __launch_bounds__(256) void colstats_bf16_kernel(const unsigned short* __restrict__ X, int M, int C,
                                                            float* __restrict__ sum, float* __restrict__ sumsq) {
  int cl = threadIdx.x & 63, rl = threadIdx.x >> 6;
  int c = blockIdx.x * 64 + cl;
  float s = 0.f, q = 0.f;
  int r0 = blockIdx.y * 256;
  int rend = min(r0 + 256, M);
  for (int r = r0 + rl; r < rend; r += 4) {
    unsigned int u = X[(size_t)r * C + c];
    float v;
    u <<= 16;
    v = *(float*)&u;
    s += v;
    q = fmaf(v, v, q);
  }
  __shared__ float ss[4][64];
  __shared__ float qq[4][64];
  ss[rl][cl] = s;
  qq[rl][cl] = q;
  __syncthreads();
  if (rl == 0) {
    s = ss[0][cl] + ss[1][cl] + ss[2][cl] + ss[3][cl];
    q = qq[0][cl] + qq[1][cl] + qq[2][cl] + qq[3][cl];
    atomicAdd(&sum[c], s);
    atomicAdd(&sumsq[c], q);
  }
}

__global__ __launch_bounds__(256) void bn_coef_kernel(const float* __restrict__ sum, const float* __restrict__ sumsq,
                                                      const float* __restrict__ g, const float* __restrict__ be,
                                                      float* __restrict__ a, float* __restrict__ b, int C, float invM) {
  int c = blockIdx.x * blockDim.x + threadIdx.x;
  if (c >= C) return;
  float mu = sum[c] * invM;
  float var = sumsq[c] * invM - mu * mu;
  float s = g[c] * rsqrtf(var + 1e-5f);
  a[c] = s;
  b[c] = be[c] - mu * s;
}

// pooled is already the mean
__global__ __launch_bounds__(256) void head_kernel(const float* __restrict__ pooled,
                                                   const float* __restrict__ m3, const float* __restrict__ a3,
                                                   const float* __restrict__ b3, const float* __restrict__ Wout,
                                                   const float* __restrict__ bout, float* __restrict__ out, int B) {
  int b = blockIdx.x * blockDim.x + threadIdx.x;
  if (b >= B) return;
  float acc = bout[0];
#pragma unroll
  for (int j = 0; j < 32; j++) acc = fmaf(pooled[(size_t)b * 32 + j], Wout[j], acc);
#pragma unroll
  for (int j = 0; j < 64; j++) acc = fmaf(fmaf(m3[(size_t)b * 64 + j], a3[j], b3[j]), Wout[32 + j], acc);
  out[b] = 1.f / (1.f + expf(-acc));
}

extern "C" void kernel_launch(void* const* d_in, const int* in_sizes, int n_in,
                              void* d_out, int out_size, void* d_ws, size_t ws_size,
                              hipStream_t stream) {
  const float* x = (const float*)d_in[0];
  const int* eidx = (const int*)d_in[1];
  const int* batch = (const int*)d_in[2];
  const float* xmord = (const float*)d_in[3];
  const float* Wl1 = (const float*)d_in[4];
  const float* bl1 = (const float*)d_in[5];
  const float* Wr1 = (const float*)d_in[6];
  const float* Wl2 = (const float*)d_in[7];
  const float* bl2 = (const float*)d_in[8];
  const float* Wr2 = (const float*)d_in[9];
  const float* Wl3 = (const float*)d_in[10];
  const float* bl3 = (const float*)d_in[11];
  const float* Wr3 = (const float*)d_in[12];
  const float* Wf1 = (const float*)d_in[13];
  const float* bf1 = (const float*)d_in[14];
  const float* g1 = (const float*)d_in[15];
  const float* be1 = (const float*)d_in[16];
  const float* Wf2 = (const float*)d_in[17];
  const float* bf2 = (const float*)d_in[18];
  const float* g2 = (const float*)d_in[19];
  const float* be2 = (const float*)d_in[20];
  const float* Wf3 = (const float*)d_in[21];
  const float* bf3 = (const float*)d_in[22];
  const float* g3 = (const float*)d_in[23];
  const float* be3 = (const float*)d_in[24];
  const float* Wout = (const float*)d_in[25];
  const float* bout = (const float*)d_in[26];
  float* out = (float*)d_out;

  const int N = in_sizes[2];
  const int E = in_sizes[1] / 2;
  const int B = in_sizes[3] / MORD;
  const int Kp1 = 896;
  const int NB = (N + 1023) / 1024;
  const int* src = eidx;
  const int* dst = eidx + E;

  char* ws = (char*)d_ws;
  size_t off_ = 0;
  auto alloc = [&](size_t bytes) { size_t o = off_; off_ += (bytes + 255) & ~(size_t)255; return o; };
  size_t oH1 = alloc((size_t)N * 32 * 4);
  size_t oH2 = alloc((size_t)N * 32 * 4);
  size_t oDeg = alloc((size_t)N * 4);
  size_t oOff = alloc((size_t)(N + 1) * 4);
  size_t oCur = alloc((size_t)N * 4);
  size_t oCsr = alloc((size_t)E * 4);
  size_t oGoff = alloc((size_t)(B + 1) * 4);
  size_t oBsum = alloc(1024 * 4);
  size_t oPool = alloc((size_t)B * 32 * 4);
  size_t oStats = alloc(4096 * 4);
  (void)ws_size;

  float* H1 = (float*)(ws + oH1);
  float* H2 = (float*)(ws + oH2);
  int* deg = (int*)(ws + oDeg);
  int* offp = (int*)(ws + oOff);
  int* cursor = (int*)(ws + oCur);
  int* csr = (int*)(ws + oCsr);
  int* goff = (int*)(ws + oGoff);
  int* bsum = (int*)(ws + oBsum);
  float* pooled = (float*)(ws + oPool);
  float* st = (float*)(ws + oStats);
  float *s1 = st, *q1 = st + 512, *a1 = st + 1024, *h1 = st + 1536;
  float *s2 = st + 2048, *q2 = st + 2176, *a2 = st + 2304, *h2 = st + 2432;
  float *s3 = st + 2560, *q3 = st + 2624, *a3 = st + 2688, *h3 = st + 2752;

  // MLP overlays (lifetimes stream-serialized): H2 region free after mfconv3; H1 free after pool_seg
  unsigned short* Abf = (unsigned short*)(ws + oH2);
  unsigned short* Bbf1 = (unsigned short*)(ws + oH2 + 29360128);
  unsigned short* W2p = (unsigned short*)(ws + oH2 + 29360128 + 917504);
  float* b2p = (float*)(ws + oH2 + 29360128 + 917504 + 131072);
  unsigned short* m1 = (unsigned short*)(ws + oH1);
  float* m2 = (float*)(ws + oH1 + 16777216);
  float* m3 = (float*)(ws + oH1 + 25165824);

  hipMemsetAsync(deg, 0, (size_t)N * 4, stream);
  hipMemsetAsync(st, 0, 4096 * 4, stream);

  // CSR build
  deg_kernel<<<(E + 255) / 256, 256, 0, stream>>>(dst, deg, E);
  scan_block<<<NB, 256, 0, stream>>>(deg, bsum, N);
  scan_bsum<<<1, 1024, 0, stream>>>(bsum, NB);
  scan_write<<<NB, 256, 0, stream>>>(deg, bsum, offp, cursor, N, E);
  csr_fill<<<(E + 255) / 256, 256, 0, stream>>>(src, dst, cursor, csr, E);
  graph_off<<<(B + 1 + 255) / 256, 256, 0, stream>>>(batch, goff, N, B);

  // GNN layers (fused gather+transform)
  mfconv_fused<8, true><<<1024, 512, 0, stream>>>(x, offp, csr, Wl1, bl1, Wr1, H1, N);
  mfconv_fused<32, true><<<512, 512, 0, stream>>>(H1, offp, csr, Wl2, bl2, Wr2, H2, N);
  mfconv_fused<32, false><<<512, 512, 0, stream>>>(H2, offp, csr, Wl3, bl3, Wr3, H1, N);

  pool_seg<<<(B * 64 + 255) / 256, 256, 0, stream>>>(H1, goff, pooled, B);

  // ---- MLP head (bf16 MFMA for fc1/fc2) ----
  cvt_bf16_pad<<<(B * (Kp1 / 4) + 255) / 256, 256, 0, stream>>>(xmord, Abf, B, MORD, Kp1);
  cvt_bf16_pad<<<(512 * (Kp1 / 4) + 255) / 256, 256, 0, stream>>>(Wf1, Bbf1, 512, MORD, Kp1);

  gemm_mfma<1><<<dim3(512 / 128, B / 128), 256, 0, stream>>>(Abf, Bbf1, bf1, m1, B, 512, Kp1);
  colstats_bf16_kernel<<<dim3(512 / 64, B / 256), 256, 0, stream>>>(m1, B, 512, s1, q1);
  bn_coef_kernel<<<2, 256, 0, stream>>>(s1, q1, g1, be1, a1, h1, 512, 1.f / B);

  prepW2_kernel<<<32, 256, 0, stream>>>(Wf2, bf2, a1, h1, W2p, b2p, 128, 512);
  gemm_mfma<0><<<dim3(128 / 128, B / 128), 256, 0, stream>>>(m1, W2p, b2p, m2, B, 128, 512);
  colstats_kernel<<<dim3(128 / 64, B / 256), 256, 0, stream>>>(m2, B, 128, s2, q2);
  bn_coef_kernel<<<1, 256, 0, stream>>>(s2, q2, g2, be2, a2, h2, 128, 1.f / B);

  gemm_bias<true><<<dim3(64 / 64, B / 64), 256, 0, stream>>>(m2, Wf3, bf3, a2, h2, m3, B, 64, 128);
  colstats_kernel<<<dim3(1, B / 256), 256, 0, stream>>>(m3, B, 64, s3, q3);
  bn_coef_kernel<<<1, 256, 0, stream>>>(s3, q3, g3, be3, a3, h3, 64, 1.f / B);

  head_kernel<<<(B + 255) / 256, 256, 0, stream>>>(pooled, m3, a3, h3, Wout, bout, out, B);
}

// Round 5
// 676.764 us; speedup vs baseline: 1.6617x; 1.6617x over previous
//
#include <hip/hip_runtime.h>
#include <hip/hip_bf16.h>
#include <math.h>

#define MORD 862

typedef short s16x8 __attribute__((ext_vector_type(8)));
typedef float f32x4 __attribute__((ext_vector_type(4)));

static __device__ __forceinline__ unsigned short f2bf(float v) {
  __hip_bfloat16 h = __float2bfloat16(v);
  return *(unsigned short*)&h;
}

__global__ __launch_bounds__(256) void deg_kernel(const int* __restrict__ dst, int* __restrict__ deg, int E) {
  int e = blockIdx.x * blockDim.x + threadIdx.x;
  if (e < E) atomicAdd(&deg[dst[e]], 1);
}

// ---- CSR build: 2-level exclusive scan of deg ----
__global__ __launch_bounds__(256) void scan_block(const int* __restrict__ deg, int* __restrict__ bsum, int N) {
  __shared__ int ts[256];
  int base = blockIdx.x * 1024 + threadIdx.x * 4;
  int s = 0;
#pragma unroll
  for (int j = 0; j < 4; j++) {
    int i = base + j;
    if (i < N) s += deg[i];
  }
  ts[threadIdx.x] = s;
  __syncthreads();
  for (int st = 128; st > 0; st >>= 1) {
    if (threadIdx.x < st) ts[threadIdx.x] += ts[threadIdx.x + st];
    __syncthreads();
  }
  if (threadIdx.x == 0) bsum[blockIdx.x] = ts[0];
}

__global__ __launch_bounds__(1024) void scan_bsum(int* __restrict__ bsum, int nb) {
  __shared__ int ts[1024];
  int tid = threadIdx.x;
  int v = (tid < nb) ? bsum[tid] : 0;
  ts[tid] = v;
  __syncthreads();
  for (int st = 1; st < 1024; st <<= 1) {
    int t = (tid >= st) ? ts[tid - st] : 0;
    __syncthreads();
    ts[tid] += t;
    __syncthreads();
  }
  if (tid < nb) bsum[tid] = ts[tid] - v;  // exclusive
}

__global__ __launch_bounds__(256) void scan_write(const int* __restrict__ deg, const int* __restrict__ bsum,
                                                  int* __restrict__ off, int* __restrict__ cursor, int N, int E) {
  __shared__ int ts[256];
  int tid = threadIdx.x;
  int base = blockIdx.x * 1024 + tid * 4;
  int v[4];
  int s = 0;
#pragma unroll
  for (int j = 0; j < 4; j++) {
    int i = base + j;
    v[j] = (i < N) ? deg[i] : 0;
    s += v[j];
  }
  int own = s;
  ts[tid] = s;
  __syncthreads();
  for (int st = 1; st < 256; st <<= 1) {
    int t = (tid >= st) ? ts[tid - st] : 0;
    __syncthreads();
    ts[tid] += t;
    __syncthreads();
  }
  int pre = ts[tid] - own + bsum[blockIdx.x];
#pragma unroll
  for (int j = 0; j < 4; j++) {
    int i = base + j;
    if (i < N) {
      off[i] = pre;
      cursor[i] = pre;
      pre += v[j];
    }
  }
  if (blockIdx.x == 0 && tid == 0) off[N] = E;
}

__global__ __launch_bounds__(256) void csr_fill(const int* __restrict__ src, const int* __restrict__ dst,
                                                int* __restrict__ cursor, int* __restrict__ csr, int E) {
  int e = blockIdx.x * blockDim.x + threadIdx.x;
  if (e < E) {
    int p = atomicAdd(&cursor[dst[e]], 1);
    csr[p] = src[e];
  }
}

__global__ __launch_bounds__(256) void graph_off(const int* __restrict__ batch, int* __restrict__ goff, int N, int B) {
  int b = blockIdx.x * blockDim.x + threadIdx.x;
  if (b > B) return;
  int lo = 0, hi = N;
  while (lo < hi) {
    int mid = (lo + hi) >> 1;
    if (batch[mid] < b) lo = mid + 1; else hi = mid;
  }
  goff[b] = lo;
}

// High-occupancy CSR gather: thread per (node, float4 chunk). No LDS, no atomics, no memset.
template <int C>
__global__ __launch_bounds__(256) void gather_csr(const float* __restrict__ xin, const int* __restrict__ off,
                                                  const int* __restrict__ csr, float* __restrict__ agg, int N) {
  const int Q = C / 4;
  long long tid = (long long)blockIdx.x * blockDim.x + threadIdx.x;
  if (tid >= (long long)N * Q) return;
  int n = (int)(tid / Q), q = (int)(tid % Q);
  int a = off[n], b = off[n + 1];
  f32x4 s = {0.f, 0.f, 0.f, 0.f};
  for (int j = a; j < b; j++) {
    const f32x4 v = *(const f32x4*)&xin[(size_t)csr[j] * C + q * 4];
    s += v;
  }
  *(f32x4*)&agg[(size_t)n * C + q * 4] = s;
}

// LDS-staged weights, transposed [d][i][o]; degree from CSR offsets. 512 threads, 16 nodes/iter.
template <int CIN, bool RELU>
__global__ __launch_bounds__(512) void transform_lds(const float* __restrict__ hagg, const float* __restrict__ xin,
                                                     const int* __restrict__ off,
                                                     const float* __restrict__ Wl, const float* __restrict__ bl,
                                                     const float* __restrict__ Wr,
                                                     float* __restrict__ out, int N) {
  __shared__ float swl[11 * CIN * 32];
  __shared__ float swr[11 * CIN * 32];
  __shared__ float sbl[11 * 32];
  __shared__ float sh[16 * CIN];
  __shared__ float sx[16 * CIN];

  for (int idx = threadIdx.x; idx < 11 * CIN * 32; idx += 512) {
    int d = idx / (CIN * 32);
    int i = (idx >> 5) % CIN;
    int o = idx & 31;
    swl[idx] = Wl[((size_t)d * 32 + o) * CIN + i];
    swr[idx] = Wr[((size_t)d * 32 + o) * CIN + i];
  }
  for (int idx = threadIdx.x; idx < 11 * 32; idx += 512) sbl[idx] = bl[idx];
  __syncthreads();

  int o = threadIdx.x & 31, ns = threadIdx.x >> 5;
  for (long long n0 = (long long)blockIdx.x * 16; n0 < N; n0 += (long long)gridDim.x * 16) {
    long long remain = (long long)N - n0;
    int cnt = remain < 16 ? (int)remain : 16;
    __syncthreads();
    for (int idx = threadIdx.x; idx < cnt * CIN; idx += 512) {
      sh[idx] = hagg[n0 * CIN + idx];
      sx[idx] = xin[n0 * CIN + idx];
    }
    __syncthreads();
    long long n = n0 + ns;
    if (ns < cnt) {
      int dg = off[n + 1] - off[n];
      int d = dg < 10 ? dg : 10;
      int wb = d * CIN * 32 + o;
      float acc = sbl[d * 32 + o];
#pragma unroll
      for (int i = 0; i < CIN; i++)
        acc = fmaf(swl[wb + i * 32], sh[ns * CIN + i], fmaf(swr[wb + i * 32], sx[ns * CIN + i], acc));
      if (RELU) acc = fmaxf(acc, 0.f);
      out[n * 32 + o] = acc;
    }
  }
}

// one wave per graph; writes mean directly (no atomics)
__global__ __launch_bounds__(256) void pool_seg(const float* __restrict__ h, const int* __restrict__ goff,
                                                float* __restrict__ pooled, int B) {
  int w = (int)((blockIdx.x * 256 + threadIdx.x) >> 6);
  if (w >= B) return;
  int lane = threadIdx.x & 63;
  int c = lane & 31, r2 = lane >> 5;
  int a = goff[w], b = goff[w + 1];
  float s = 0.f;
  for (int r = a + r2; r < b; r += 2) s += h[(size_t)r * 32 + c];
  s += __shfl_down(s, 32);
  if (r2 == 0) pooled[(size_t)w * 32 + c] = s / fmaxf((float)(b - a), 1.f);
}

// fp32 -> bf16 with K padding to Kp (zeros in pad)
__global__ __launch_bounds__(256) void cvt_bf16_pad(const float* __restrict__ src, unsigned short* __restrict__ dst,
                                                    int rows, int K, int Kp) {
  int t = blockIdx.x * blockDim.x + threadIdx.x;
  int q = Kp / 4;
  if (t >= rows * q) return;
  int r = t / q, c4 = (t % q) * 4;
#pragma unroll
  for (int j = 0; j < 4; j++) {
    int k = c4 + j;
    float v = (k < K) ? src[(size_t)r * K + k] : 0.f;
    dst[(size_t)r * Kp + k] = f2bf(v);
  }
}

__global__ __launch_bounds__(256) void prepW2_kernel(const float* __restrict__ W2, const float* __restrict__ b2,
                                                     const float* __restrict__ a1, const float* __restrict__ h1,
                                                     unsigned short* __restrict__ W2p, float* __restrict__ b2p,
                                                     int Nn, int K) {
  int wid = threadIdx.x >> 6, lane = threadIdx.x & 63;
  int n = blockIdx.x * 4 + wid;
  if (n >= Nn) return;
  float part = 0.f;
  for (int k = lane; k < K; k += 64) {
    float w = W2[(size_t)n * K + k];
    W2p[(size_t)n * K + k] = f2bf(w * a1[k]);
    part = fmaf(w, h1[k], part);
  }
#pragma unroll
  for (int off = 32; off > 0; off >>= 1) part += __shfl_down(part, off, 64);
  if (lane == 0) b2p[n] = b2[n] + part;
}

// bf16 MFMA GEMM: C[M,Nn] = relu(A[M,Kp] @ Bw[Nn,Kp]^T + bias). 128x128 tile, BK=64.
template <int OUTBF16>
__global__ __launch_bounds__(256) void gemm_mfma(const unsigned short* __restrict__ A,
                                                 const unsigned short* __restrict__ Bw,
                                                 const float* __restrict__ bias,
                                                 void* __restrict__ Cout, int M, int Nn, int Kp) {
  __shared__ unsigned short As[128 * 64];
  __shared__ unsigned short Bs[128 * 64];
  int tid = threadIdx.x;
  int wid = tid >> 6, lane = tid & 63;
  int m0 = blockIdx.y * 128, n0 = blockIdx.x * 128;
  int wr = wid >> 1, wc = wid & 1;
  f32x4 acc[4][4] = {};

  int srow_l = lane >> 3;
  int scol = (lane & 7) * 8;
  int aReadBase = ((wr * 64 + (lane & 15)) * 128) + ((lane >> 4) * 16);
  int bReadBase = ((wc * 64 + (lane & 15)) * 128) + ((lane >> 4) * 16);

  const unsigned short* Ablk = A + (size_t)m0 * Kp;
  const unsigned short* Bblk = Bw + (size_t)n0 * Kp;

  for (int k0 = 0; k0 < Kp; k0 += 64) {
#pragma unroll
    for (int i = 0; i < 4; i++) {
      int s = wid * 4 + i;
      int row = s * 8 + srow_l;
      const unsigned short* ga = Ablk + (size_t)row * Kp + k0 + scol;
      const unsigned short* gb = Bblk + (size_t)row * Kp + k0 + scol;
      __builtin_amdgcn_global_load_lds((const __attribute__((address_space(1))) void*)ga,
                                       (__attribute__((address_space(3))) void*)(As + s * 512), 16, 0, 0);
      __builtin_amdgcn_global_load_lds((const __attribute__((address_space(1))) void*)gb,
                                       (__attribute__((address_space(3))) void*)(Bs + s * 512), 16, 0, 0);
    }
    __syncthreads();
#pragma unroll
    for (int kk = 0; kk < 2; kk++) {
      s16x8 af[4], bfr[4];
#pragma unroll
      for (int m = 0; m < 4; m++)
        af[m] = *(const s16x8*)((const char*)As + aReadBase + m * (16 * 128) + kk * 64);
#pragma unroll
      for (int n = 0; n < 4; n++)
        bfr[n] = *(const s16x8*)((const char*)Bs + bReadBase + n * (16 * 128) + kk * 64);
#pragma unroll
      for (int m = 0; m < 4; m++)
#pragma unroll
        for (int n = 0; n < 4; n++)
          acc[m][n] = __builtin_amdgcn_mfma_f32_16x16x32_bf16(af[m], bfr[n], acc[m][n], 0, 0, 0);
    }
    __syncthreads();
  }

  int rbase = m0 + wr * 64 + (lane >> 4) * 4;
  int cbase = n0 + wc * 64 + (lane & 15);
#pragma unroll
  for (int m = 0; m < 4; m++)
#pragma unroll
    for (int n = 0; n < 4; n++) {
      int col = cbase + n * 16;
      float bv = bias[col];
#pragma unroll
      for (int j = 0; j < 4; j++) {
        int row = rbase + m * 16 + j;
        float v = fmaxf(acc[m][n][j] + bv, 0.f);
        if (OUTBF16)
          ((unsigned short*)Cout)[(size_t)row * Nn + col] = f2bf(v);
        else
          ((float*)Cout)[(size_t)row * Nn + col] = v;
      }
    }
}

// fp32 fallback GEMM (used for fc3)
template <bool RELU>
__global__ __launch_bounds__(256) void gemm_bias(const float* __restrict__ A, const float* __restrict__ Bw,
                                                 const float* __restrict__ bias,
                                                 const float* __restrict__ scA, const float* __restrict__ shA,
                                                 float* __restrict__ C, int M, int Nn, int K) {
  const int BM = 64, BN = 64, BK = 16;
  __shared__ float As[BK][BM + 1];
  __shared__ float Bs[BK][BN + 1];
  int bm = blockIdx.y * BM, bn = blockIdx.x * BN;
  int tid = threadIdx.x;
  int tr = tid / 16, tc = tid % 16;
  float acc[4][4] = {};
  for (int k0 = 0; k0 < K; k0 += BK) {
    for (int i = tid; i < BM * BK; i += 256) {
      int m = i / BK, k = i % BK;
      float v = 0.f;
      if (k0 + k < K) {
        v = A[(size_t)(bm + m) * K + k0 + k];
        if (scA) v = fmaf(v, scA[k0 + k], shA[k0 + k]);
      }
      As[k][m] = v;
    }
    for (int i = tid; i < BN * BK; i += 256) {
      int n = i / BK, k = i % BK;
      float v = 0.f;
      if (k0 + k < K) v = Bw[(size_t)(bn + n) * K + k0 + k];
      Bs[k][n] = v;
    }
    __syncthreads();
#pragma unroll
    for (int k = 0; k < BK; k++) {
      float a4[4], b4[4];
#pragma unroll
      for (int xx = 0; xx < 4; xx++) a4[xx] = As[k][tr * 4 + xx];
#pragma unroll
      for (int yy = 0; yy < 4; yy++) b4[yy] = Bs[k][tc * 4 + yy];
#pragma unroll
      for (int xx = 0; xx < 4; xx++)
#pragma unroll
        for (int yy = 0; yy < 4; yy++) acc[xx][yy] = fmaf(a4[xx], b4[yy], acc[xx][yy]);
    }
    __syncthreads();
  }
  for (int xx = 0; xx < 4; xx++) {
    int m = bm + tr * 4 + xx;
    for (int yy = 0; yy < 4; yy++) {
      int n = bn + tc * 4 + yy;
      float v = acc[xx][yy] + bias[n];
      if (RELU) v = fmaxf(v, 0.f);
      C[(size_t)m * Nn + n] = v;
    }
  }
}

__global__ __launch_bounds__(256) void colstats_kernel(const float* __restrict__ X, int M, int C,
                                                       float* __restrict__ sum, float* __restrict__ sumsq) {
  int cl = threadIdx.x & 63, rl = threadIdx.x >> 6;
  int c = blockIdx.x * 64 + cl;
  float s = 0.f, q = 0.f;
  int r0 = blockIdx.y * 256;
  int rend = min(r0 + 256, M);
  for (int r = r0 + rl; r < rend; r += 4) {
    float v = X[(size_t)r * C + c];
    s += v;
    q = fmaf(v, v, q);
  }
  __shared__ float ss[4][64];
  __shared__ float qq[4][64];
  ss[rl][cl] = s;
  qq[rl][cl] = q;
  __syncthreads();
  if (rl == 0) {
    s = ss[0][cl] + ss[1][cl] + ss[2][cl] + ss[3][cl];
    q = qq[0][cl] + qq[1][cl] + qq[2][cl] + qq[3][cl];
    atomicAdd(&sum[c], s);
    atomicAdd(&sumsq[c], q);
  }
}

__global__ __launch_bounds__(256) void colstats_bf16_kernel(const unsigned short* __restrict__ X, int M, int C,
                                                            float* __restrict__ sum, float* __restrict__ sumsq) {
  int cl = threadIdx.x & 63, rl = threadIdx.x >> 6;
  int c = blockIdx.x * 64 + cl;
  float s = 0.f, q = 0.f;
  int r0 = blockIdx.y * 256;
  int rend = min(r0 + 256, M);
  for (int r = r0 + rl; r < rend; r += 4) {
    unsigned int u = X[(size_t)r * C + c];
    float v;
    u <<= 16;
    v = *(float*)&u;
    s += v;
    q = fmaf(v, v, q);
  }
  __shared__ float ss[4][64];
  __shared__ float qq[4][64];
  ss[rl][cl] = s;
  qq[rl][cl] = q;
  __syncthreads();
  if (rl == 0) {
    s = ss[0][cl] + ss[1][cl] + ss[2][cl] + ss[3][cl];
    q = qq[0][cl] + qq[1][cl] + qq[2][cl] + qq[3][cl];
    atomicAdd(&sum[c], s);
    atomicAdd(&sumsq[c], q);
  }
}

__global__ __launch_bounds__(256) void bn_coef_kernel(const float* __restrict__ sum, const float* __restrict__ sumsq,
                                                      const float* __restrict__ g, const float* __restrict__ be,
                                                      float* __restrict__ a, float* __restrict__ b, int C, float invM) {
  int c = blockIdx.x * blockDim.x + threadIdx.x;
  if (c >= C) return;
  float mu = sum[c] * invM;
  float var = sumsq[c] * invM - mu * mu;
  float s = g[c] * rsqrtf(var + 1e-5f);
  a[c] = s;
  b[c] = be[c] - mu * s;
}

__global__ __launch_bounds__(256) void head_kernel(const float* __restrict__ pooled,
                                                   const float* __restrict__ m3, const float* __restrict__ a3,
                                                   const float* __restrict__ b3, const float* __restrict__ Wout,
                                                   const float* __restrict__ bout, float* __restrict__ out, int B) {
  int b = blockIdx.x * blockDim.x + threadIdx.x;
  if (b >= B) return;
  float acc = bout[0];
#pragma unroll
  for (int j = 0; j < 32; j++) acc = fmaf(pooled[(size_t)b * 32 + j], Wout[j], acc);
#pragma unroll
  for (int j = 0; j < 64; j++) acc = fmaf(fmaf(m3[(size_t)b * 64 + j], a3[j], b3[j]), Wout[32 + j], acc);
  out[b] = 1.f / (1.f + expf(-acc));
}

extern "C" void kernel_launch(void* const* d_in, const int* in_sizes, int n_in,
                              void* d_out, int out_size, void* d_ws, size_t ws_size,
                              hipStream_t stream) {
  const float* x = (const float*)d_in[0];
  const int* eidx = (const int*)d_in[1];
  const int* batch = (const int*)d_in[2];
  const float* xmord = (const float*)d_in[3];
  const float* Wl1 = (const float*)d_in[4];
  const float* bl1 = (const float*)d_in[5];
  const float* Wr1 = (const float*)d_in[6];
  const float* Wl2 = (const float*)d_in[7];
  const float* bl2 = (const float*)d_in[8];
  const float* Wr2 = (const float*)d_in[9];
  const float* Wl3 = (const float*)d_in[10];
  const float* bl3 = (const float*)d_in[11];
  const float* Wr3 = (const float*)d_in[12];
  const float* Wf1 = (const float*)d_in[13];
  const float* bf1 = (const float*)d_in[14];
  const float* g1 = (const float*)d_in[15];
  const float* be1 = (const float*)d_in[16];
  const float* Wf2 = (const float*)d_in[17];
  const float* bf2 = (const float*)d_in[18];
  const float* g2 = (const float*)d_in[19];
  const float* be2 = (const float*)d_in[20];
  const float* Wf3 = (const float*)d_in[21];
  const float* bf3 = (const float*)d_in[22];
  const float* g3 = (const float*)d_in[23];
  const float* be3 = (const float*)d_in[24];
  const float* Wout = (const float*)d_in[25];
  const float* bout = (const float*)d_in[26];
  float* out = (float*)d_out;

  const int N = in_sizes[2];
  const int E = in_sizes[1] / 2;
  const int B = in_sizes[3] / MORD;
  const int Kp1 = 896;
  const int NB = (N + 1023) / 1024;
  const int* src = eidx;
  const int* dst = eidx + E;

  char* ws = (char*)d_ws;
  size_t off_ = 0;
  auto alloc = [&](size_t bytes) { size_t o = off_; off_ += (bytes + 255) & ~(size_t)255; return o; };
  size_t oH1 = alloc((size_t)N * 32 * 4);
  size_t oH2 = alloc((size_t)N * 32 * 4);
  size_t oAGG = alloc((size_t)N * 32 * 4);
  size_t oDeg = alloc((size_t)N * 4);
  size_t oOff = alloc((size_t)(N + 1) * 4);
  size_t oCur = alloc((size_t)N * 4);
  size_t oCsr = alloc((size_t)E * 4);
  size_t oGoff = alloc((size_t)(B + 1) * 4);
  size_t oBsum = alloc(1024 * 4);
  size_t oPool = alloc((size_t)B * 32 * 4);
  size_t oStats = alloc(4096 * 4);
  (void)ws_size;

  float* H1 = (float*)(ws + oH1);
  float* H2 = (float*)(ws + oH2);
  float* AGG = (float*)(ws + oAGG);
  int* deg = (int*)(ws + oDeg);
  int* offp = (int*)(ws + oOff);
  int* cursor = (int*)(ws + oCur);
  int* csr = (int*)(ws + oCsr);
  int* goff = (int*)(ws + oGoff);
  int* bsum = (int*)(ws + oBsum);
  float* pooled = (float*)(ws + oPool);
  float* st = (float*)(ws + oStats);
  float *s1 = st, *q1 = st + 512, *a1 = st + 1024, *h1 = st + 1536;
  float *s2 = st + 2048, *q2 = st + 2176, *a2 = st + 2304, *h2 = st + 2432;
  float *s3 = st + 2560, *q3 = st + 2624, *a3 = st + 2688, *h3 = st + 2752;

  // MLP overlays (lifetimes stream-serialized): H2 free after mfconv3 input use; H1 free after pool_seg
  unsigned short* Abf = (unsigned short*)(ws + oH2);
  unsigned short* Bbf1 = (unsigned short*)(ws + oH2 + 29360128);
  unsigned short* W2p = (unsigned short*)(ws + oH2 + 29360128 + 917504);
  float* b2p = (float*)(ws + oH2 + 29360128 + 917504 + 131072);
  unsigned short* m1 = (unsigned short*)(ws + oH1);
  float* m2 = (float*)(ws + oH1 + 16777216);
  float* m3 = (float*)(ws + oH1 + 25165824);

  hipMemsetAsync(deg, 0, (size_t)N * 4, stream);
  hipMemsetAsync(st, 0, 4096 * 4, stream);

  // CSR build
  deg_kernel<<<(E + 255) / 256, 256, 0, stream>>>(dst, deg, E);
  scan_block<<<NB, 256, 0, stream>>>(deg, bsum, N);
  scan_bsum<<<1, 1024, 0, stream>>>(bsum, NB);
  scan_write<<<NB, 256, 0, stream>>>(deg, bsum, offp, cursor, N, E);
  csr_fill<<<(E + 255) / 256, 256, 0, stream>>>(src, dst, cursor, csr, E);
  graph_off<<<(B + 1 + 255) / 256, 256, 0, stream>>>(batch, goff, N, B);

  // GNN layers: high-occupancy gather + LDS-weight transform
  gather_csr<8><<<(int)(((long long)N * 2 + 255) / 256), 256, 0, stream>>>(x, offp, csr, AGG, N);
  transform_lds<8, true><<<1024, 512, 0, stream>>>(AGG, x, offp, Wl1, bl1, Wr1, H1, N);

  gather_csr<32><<<(int)(((long long)N * 8 + 255) / 256), 256, 0, stream>>>(H1, offp, csr, AGG, N);
  transform_lds<32, true><<<256, 512, 0, stream>>>(AGG, H1, offp, Wl2, bl2, Wr2, H2, N);

  gather_csr<32><<<(int)(((long long)N * 8 + 255) / 256), 256, 0, stream>>>(H2, offp, csr, AGG, N);
  transform_lds<32, false><<<256, 512, 0, stream>>>(AGG, H2, offp, Wl3, bl3, Wr3, H1, N);

  pool_seg<<<(B * 64 + 255) / 256, 256, 0, stream>>>(H1, goff, pooled, B);

  // ---- MLP head (bf16 MFMA for fc1/fc2) ----
  cvt_bf16_pad<<<(B * (Kp1 / 4) + 255) / 256, 256, 0, stream>>>(xmord, Abf, B, MORD, Kp1);
  cvt_bf16_pad<<<(512 * (Kp1 / 4) + 255) / 256, 256, 0, stream>>>(Wf1, Bbf1, 512, MORD, Kp1);

  gemm_mfma<1><<<dim3(512 / 128, B / 128), 256, 0, stream>>>(Abf, Bbf1, bf1, m1, B, 512, Kp1);
  colstats_bf16_kernel<<<dim3(512 / 64, B / 256), 256, 0, stream>>>(m1, B, 512, s1, q1);
  bn_coef_kernel<<<2, 256, 0, stream>>>(s1, q1, g1, be1, a1, h1, 512, 1.f / B);

  prepW2_kernel<<<32, 256, 0, stream>>>(Wf2, bf2, a1, h1, W2p, b2p, 128, 512);
  gemm_mfma<0><<<dim3(128 / 128, B / 128), 256, 0, stream>>>(m1, W2p, b2p, m2, B, 128, 512);
  colstats_kernel<<<dim3(128 / 64, B / 256), 256, 0, stream>>>(m2, B, 128, s2, q2);
  bn_coef_kernel<<<1, 256, 0, stream>>>(s2, q2, g2, be2, a2, h2, 128, 1.f / B);

  gemm_bias<true><<<dim3(64 / 64, B / 64), 256, 0, stream>>>(m2, Wf3, bf3, a2, h2, m3, B, 64, 128);
  colstats_kernel<<<dim3(1, B / 256), 256, 0, stream>>>(m3, B, 64, s3, q3);
  bn_coef_kernel<<<1, 256, 0, stream>>>(s3, q3, g3, be3, a3, h3, 64, 1.f / B);

  head_kernel<<<(B + 255) / 256, 256, 0, stream>>>(pooled, m3, a3, h3, Wout, bout, out, B);
}

// Round 6
// 457.315 us; speedup vs baseline: 2.4591x; 1.4799x over previous
//
#include <hip/hip_runtime.h>
#include <hip/hip_bf16.h>
#include <math.h>

#define MORD 862

typedef short s16x8 __attribute__((ext_vector_type(8)));
typedef float f32x4 __attribute__((ext_vector_type(4)));

static __device__ __forceinline__ unsigned short f2bf(float v) {
  __hip_bfloat16 h = __float2bfloat16(v);
  return *(unsigned short*)&h;
}

__global__ __launch_bounds__(256) void deg_kernel(const int* __restrict__ dst, int* __restrict__ deg, int E) {
  int e = blockIdx.x * blockDim.x + threadIdx.x;
  if (e < E) atomicAdd(&deg[dst[e]], 1);
}

// ---- CSR build: 2-level exclusive scan of deg ----
__global__ __launch_bounds__(256) void scan_block(const int* __restrict__ deg, int* __restrict__ bsum, int N) {
  __shared__ int ts[256];
  int base = blockIdx.x * 1024 + threadIdx.x * 4;
  int s = 0;
#pragma unroll
  for (int j = 0; j < 4; j++) {
    int i = base + j;
    if (i < N) s += deg[i];
  }
  ts[threadIdx.x] = s;
  __syncthreads();
  for (int st = 128; st > 0; st >>= 1) {
    if (threadIdx.x < st) ts[threadIdx.x] += ts[threadIdx.x + st];
    __syncthreads();
  }
  if (threadIdx.x == 0) bsum[blockIdx.x] = ts[0];
}

__global__ __launch_bounds__(1024) void scan_bsum(int* __restrict__ bsum, int nb) {
  __shared__ int ts[1024];
  int tid = threadIdx.x;
  int v = (tid < nb) ? bsum[tid] : 0;
  ts[tid] = v;
  __syncthreads();
  for (int st = 1; st < 1024; st <<= 1) {
    int t = (tid >= st) ? ts[tid - st] : 0;
    __syncthreads();
    ts[tid] += t;
    __syncthreads();
  }
  if (tid < nb) bsum[tid] = ts[tid] - v;  // exclusive
}

__global__ __launch_bounds__(256) void scan_write(const int* __restrict__ deg, const int* __restrict__ bsum,
                                                  int* __restrict__ off, int* __restrict__ cursor, int N, int E) {
  __shared__ int ts[256];
  int tid = threadIdx.x;
  int base = blockIdx.x * 1024 + tid * 4;
  int v[4];
  int s = 0;
#pragma unroll
  for (int j = 0; j < 4; j++) {
    int i = base + j;
    v[j] = (i < N) ? deg[i] : 0;
    s += v[j];
  }
  int own = s;
  ts[tid] = s;
  __syncthreads();
  for (int st = 1; st < 256; st <<= 1) {
    int t = (tid >= st) ? ts[tid - st] : 0;
    __syncthreads();
    ts[tid] += t;
    __syncthreads();
  }
  int pre = ts[tid] - own + bsum[blockIdx.x];
#pragma unroll
  for (int j = 0; j < 4; j++) {
    int i = base + j;
    if (i < N) {
      off[i] = pre;
      cursor[i] = pre;
      pre += v[j];
    }
  }
  if (blockIdx.x == 0 && tid == 0) off[N] = E;
}

__global__ __launch_bounds__(256) void csr_fill(const int* __restrict__ src, const int* __restrict__ dst,
                                                int* __restrict__ cursor, int* __restrict__ csr, int E) {
  int e = blockIdx.x * blockDim.x + threadIdx.x;
  if (e < E) {
    int p = atomicAdd(&cursor[dst[e]], 1);
    csr[p] = src[e];
  }
}

__global__ __launch_bounds__(256) void graph_off(const int* __restrict__ batch, int* __restrict__ goff, int N, int B) {
  int b = blockIdx.x * blockDim.x + threadIdx.x;
  if (b > B) return;
  int lo = 0, hi = N;
  while (lo < hi) {
    int mid = (lo + hi) >> 1;
    if (batch[mid] < b) lo = mid + 1; else hi = mid;
  }
  goff[b] = lo;
}

// Wcat[(d*32+o)][k] bf16, K=64: k<CIN -> Wl[d][o][k]; CIN<=k<2CIN -> Wr[d][o][k-CIN]; else 0
__global__ __launch_bounds__(256) void prep_wcat(const float* __restrict__ Wl, const float* __restrict__ Wr,
                                                 unsigned short* __restrict__ Wcat, int CIN) {
  int idx = blockIdx.x * 256 + threadIdx.x;
  if (idx >= 352 * 64) return;
  int row = idx >> 6, k = idx & 63;
  int d = row >> 5, o = row & 31;
  float v = 0.f;
  if (k < CIN) v = Wl[((size_t)d * 32 + o) * CIN + k];
  else if (k < 2 * CIN) v = Wr[((size_t)d * 32 + o) * CIN + (k - CIN)];
  Wcat[idx] = f2bf(v);
}

// hx1[n][64] bf16: 0-7 = neighbor-sum(x), 8-15 = x, rest zero
__global__ __launch_bounds__(256) void prep_hx1(const float* __restrict__ x, const int* __restrict__ off,
                                                const int* __restrict__ csr, unsigned short* __restrict__ hx1, int N) {
  int n = blockIdx.x * 256 + threadIdx.x;
  if (n >= N) return;
  int a = off[n], b = off[n + 1];
  float ag[8] = {};
  for (int j = a; j < b; j++) {
    const float* xr = x + (size_t)csr[j] * 8;
#pragma unroll
    for (int t = 0; t < 8; t++) ag[t] += xr[t];
  }
  const float* xo = x + (size_t)n * 8;
  unsigned short* d = hx1 + (size_t)n * 64;
  s16x8 w0, w1, z;
#pragma unroll
  for (int t = 0; t < 8; t++) {
    w0[t] = (short)f2bf(ag[t]);
    w1[t] = (short)f2bf(xo[t]);
    z[t] = 0;
  }
  *(s16x8*)(d) = w0;
  *(s16x8*)(d + 8) = w1;
  *(s16x8*)(d + 16) = z;
  *(s16x8*)(d + 24) = z;
  *(s16x8*)(d + 32) = z;
  *(s16x8*)(d + 40) = z;
  *(s16x8*)(d + 48) = z;
  *(s16x8*)(d + 56) = z;
}

// sum neighbors' x-half (cols 32-63) into own agg-half (cols 0-31). thread = (node, 8-ch chunk)
__global__ __launch_bounds__(256) void gather_bf16(const unsigned short* __restrict__ hx, const int* __restrict__ off,
                                                   const int* __restrict__ csr, unsigned short* __restrict__ hxw, int N) {
  long long tid = (long long)blockIdx.x * 256 + threadIdx.x;
  if (tid >= (long long)N * 4) return;
  int n = (int)(tid >> 2), q = (int)(tid & 3);
  int a = off[n], b = off[n + 1];
  float s[8] = {};
  for (int j = a; j < b; j++) {
    const s16x8 v = *(const s16x8*)(hx + (size_t)csr[j] * 64 + 32 + q * 8);
#pragma unroll
    for (int t = 0; t < 8; t++) {
      unsigned int u = ((unsigned int)(unsigned short)v[t]) << 16;
      s[t] += *(float*)&u;
    }
  }
  s16x8 w;
#pragma unroll
  for (int t = 0; t < 8; t++) w[t] = (short)f2bf(s[t]);
  *(s16x8*)(hxw + (size_t)n * 64 + q * 8) = w;
}

// MFMA all-degree transform: per 128-row tile, C[128x352] = A[128x64] @ Wcat[352x64]^T;
// epilogue selects the 32 cols matching each row's degree. XOR-swizzled LDS (st-16B within 128B rows).
// OUTMODE 0: relu -> bf16 into hx_next x-half; 1: +bias -> f32 H3
template <int KS, int OUTMODE>
__global__ __launch_bounds__(512, 4) void mfconv_mfma(const unsigned short* __restrict__ hx,
                                                      const unsigned short* __restrict__ Wcat,
                                                      const float* __restrict__ bl,
                                                      const int* __restrict__ off,
                                                      void* __restrict__ outp, int N) {
  __shared__ __align__(16) unsigned short As[128 * 64];
  __shared__ __align__(16) unsigned short Bs[352 * 64];
  __shared__ float sbias[352];
  __shared__ int sdeg[128];
  const int tid = threadIdx.x;
  const int wid = tid >> 6, lane = tid & 63;

  // stage all weights once (44 KB), swizzled: LDS[c] = G[c ^ ((c>>3)&7)] so reads at c^(row&7) hit G[c]
  for (int s = wid; s < 44; s += 8) {
    int c = s * 64 + lane;
    int cs = c ^ ((c >> 3) & 7);
    __builtin_amdgcn_global_load_lds((const __attribute__((address_space(1))) void*)((const char*)Wcat + (size_t)cs * 16),
                                     (__attribute__((address_space(3))) void*)((char*)Bs + s * 1024), 16, 0, 0);
  }
  for (int i = tid; i < 352; i += 512) sbias[i] = bl[i];

  const int ntiles = N >> 7;
  for (int t = blockIdx.x; t < ntiles; t += (int)gridDim.x) {
    const int row0 = t << 7;
    __syncthreads();  // prev-iter readers done; also drains B-stage on first iter
    const char* Abase = (const char*)(hx + (size_t)row0 * 64);
    for (int s = wid; s < 16; s += 8) {
      int c = s * 64 + lane;
      int cs = c ^ ((c >> 3) & 7);
      __builtin_amdgcn_global_load_lds((const __attribute__((address_space(1))) void*)(Abase + (size_t)cs * 16),
                                       (__attribute__((address_space(3))) void*)((char*)As + s * 1024), 16, 0, 0);
    }
    if (tid < 128) sdeg[tid] = min(off[row0 + tid + 1] - off[row0 + tid], 10);
    __syncthreads();

    const int ra = wid * 16 + (lane & 15);
    const int g4 = lane >> 4;
    const int rl0 = wid * 16 + g4 * 4;
    int dj[4];
#pragma unroll
    for (int j = 0; j < 4; j++) dj[j] = sdeg[rl0 + j];

#pragma unroll
    for (int h = 0; h < 2; h++) {
      f32x4 acc[11] = {};
#pragma unroll
      for (int kk = 0; kk < KS; kk++) {
        int ca = ra * 8 + kk * 4 + g4;
        s16x8 af = *(const s16x8*)((const char*)As + (size_t)(ca ^ (ra & 7)) * 16);
#pragma unroll
        for (int nn = 0; nn < 11; nn++) {
          int rb = (h * 11 + nn) * 16 + (lane & 15);
          int cb = rb * 8 + kk * 4 + g4;
          s16x8 bf = *(const s16x8*)((const char*)Bs + (size_t)(cb ^ (rb & 7)) * 16);
          acc[nn] = __builtin_amdgcn_mfma_f32_16x16x32_bf16(af, bf, acc[nn], 0, 0, 0);
        }
      }
#pragma unroll
      for (int nn = 0; nn < 11; nn++) {
        int n = h * 11 + nn;
        int dsel = n >> 1;
        int o = (n & 1) * 16 + (lane & 15);
        float bv = sbias[dsel * 32 + o];
#pragma unroll
        for (int j = 0; j < 4; j++) {
          if (dj[j] == dsel) {
            float v = acc[nn][j] + bv;
            size_t gr = (size_t)row0 + rl0 + j;
            if (OUTMODE == 0) {
              v = fmaxf(v, 0.f);
              ((unsigned short*)outp)[gr * 64 + 32 + o] = f2bf(v);
            } else {
              ((float*)outp)[gr * 32 + o] = v;
            }
          }
        }
      }
    }
  }
}

// one wave per graph; writes mean directly (no atomics)
__global__ __launch_bounds__(256) void pool_seg(const float* __restrict__ h, const int* __restrict__ goff,
                                                float* __restrict__ pooled, int B) {
  int w = (int)((blockIdx.x * 256 + threadIdx.x) >> 6);
  if (w >= B) return;
  int lane = threadIdx.x & 63;
  int c = lane & 31, r2 = lane >> 5;
  int a = goff[w], b = goff[w + 1];
  float s = 0.f;
  for (int r = a + r2; r < b; r += 2) s += h[(size_t)r * 32 + c];
  s += __shfl_down(s, 32);
  if (r2 == 0) pooled[(size_t)w * 32 + c] = s / fmaxf((float)(b - a), 1.f);
}

// fp32 -> bf16 with K padding to Kp (zeros in pad)
__global__ __launch_bounds__(256) void cvt_bf16_pad(const float* __restrict__ src, unsigned short* __restrict__ dst,
                                                    int rows, int K, int Kp) {
  int t = blockIdx.x * blockDim.x + threadIdx.x;
  int q = Kp / 4;
  if (t >= rows * q) return;
  int r = t / q, c4 = (t % q) * 4;
#pragma unroll
  for (int j = 0; j < 4; j++) {
    int k = c4 + j;
    float v = (k < K) ? src[(size_t)r * K + k] : 0.f;
    dst[(size_t)r * Kp + k] = f2bf(v);
  }
}

__global__ __launch_bounds__(256) void prepW2_kernel(const float* __restrict__ W2, const float* __restrict__ b2,
                                                     const float* __restrict__ a1, const float* __restrict__ h1,
                                                     unsigned short* __restrict__ W2p, float* __restrict__ b2p,
                                                     int Nn, int K) {
  int wid = threadIdx.x >> 6, lane = threadIdx.x & 63;
  int n = blockIdx.x * 4 + wid;
  if (n >= Nn) return;
  float part = 0.f;
  for (int k = lane; k < K; k += 64) {
    float w = W2[(size_t)n * K + k];
    W2p[(size_t)n * K + k] = f2bf(w * a1[k]);
    part = fmaf(w, h1[k], part);
  }
#pragma unroll
  for (int off = 32; off > 0; off >>= 1) part += __shfl_down(part, off, 64);
  if (lane == 0) b2p[n] = b2[n] + part;
}

// bf16 MFMA GEMM: C[M,Nn] = relu(A[M,Kp] @ Bw[Nn,Kp]^T + bias). 128x128 tile, BK=64.
template <int OUTBF16>
__global__ __launch_bounds__(256) void gemm_mfma(const unsigned short* __restrict__ A,
                                                 const unsigned short* __restrict__ Bw,
                                                 const float* __restrict__ bias,
                                                 void* __restrict__ Cout, int M, int Nn, int Kp) {
  __shared__ __align__(16) unsigned short As[128 * 64];
  __shared__ __align__(16) unsigned short Bs[128 * 64];
  int tid = threadIdx.x;
  int wid = tid >> 6, lane = tid & 63;
  int m0 = blockIdx.y * 128, n0 = blockIdx.x * 128;
  int wr = wid >> 1, wc = wid & 1;
  f32x4 acc[4][4] = {};

  int srow_l = lane >> 3;
  int scol = (lane & 7) * 8;
  int aReadBase = ((wr * 64 + (lane & 15)) * 128) + ((lane >> 4) * 16);
  int bReadBase = ((wc * 64 + (lane & 15)) * 128) + ((lane >> 4) * 16);

  const unsigned short* Ablk = A + (size_t)m0 * Kp;
  const unsigned short* Bblk = Bw + (size_t)n0 * Kp;

  for (int k0 = 0; k0 < Kp; k0 += 64) {
#pragma unroll
    for (int i = 0; i < 4; i++) {
      int s = wid * 4 + i;
      int row = s * 8 + srow_l;
      const unsigned short* ga = Ablk + (size_t)row * Kp + k0 + scol;
      const unsigned short* gb = Bblk + (size_t)row * Kp + k0 + scol;
      __builtin_amdgcn_global_load_lds((const __attribute__((address_space(1))) void*)ga,
                                       (__attribute__((address_space(3))) void*)(As + s * 512), 16, 0, 0);
      __builtin_amdgcn_global_load_lds((const __attribute__((address_space(1))) void*)gb,
                                       (__attribute__((address_space(3))) void*)(Bs + s * 512), 16, 0, 0);
    }
    __syncthreads();
#pragma unroll
    for (int kk = 0; kk < 2; kk++) {
      s16x8 af[4], bfr[4];
#pragma unroll
      for (int m = 0; m < 4; m++)
        af[m] = *(const s16x8*)((const char*)As + aReadBase + m * (16 * 128) + kk * 64);
#pragma unroll
      for (int n = 0; n < 4; n++)
        bfr[n] = *(const s16x8*)((const char*)Bs + bReadBase + n * (16 * 128) + kk * 64);
#pragma unroll
      for (int m = 0; m < 4; m++)
#pragma unroll
        for (int n = 0; n < 4; n++)
          acc[m][n] = __builtin_amdgcn_mfma_f32_16x16x32_bf16(af[m], bfr[n], acc[m][n], 0, 0, 0);
    }
    __syncthreads();
  }

  int rbase = m0 + wr * 64 + (lane >> 4) * 4;
  int cbase = n0 + wc * 64 + (lane & 15);
#pragma unroll
  for (int m = 0; m < 4; m++)
#pragma unroll
    for (int n = 0; n < 4; n++) {
      int col = cbase + n * 16;
      float bv = bias[col];
#pragma unroll
      for (int j = 0; j < 4; j++) {
        int row = rbase + m * 16 + j;
        float v = fmaxf(acc[m][n][j] + bv, 0.f);
        if (OUTBF16)
          ((unsigned short*)Cout)[(size_t)row * Nn + col] = f2bf(v);
        else
          ((float*)Cout)[(size_t)row * Nn + col] = v;
      }
    }
}

// fp32 fallback GEMM (used for fc3)
template <bool RELU>
__global__ __launch_bounds__(256) void gemm_bias(const float* __restrict__ A, const float* __restrict__ Bw,
                                                 const float* __restrict__ bias,
                                                 const float* __restrict__ scA, const float* __restrict__ shA,
                                                 float* __restrict__ C, int M, int Nn, int K) {
  const int BM = 64, BN = 64, BK = 16;
  __shared__ float As[BK][BM + 1];
  __shared__ float Bs[BK][BN + 1];
  int bm = blockIdx.y * BM, bn = blockIdx.x * BN;
  int tid = threadIdx.x;
  int tr = tid / 16, tc = tid % 16;
  float acc[4][4] = {};
  for (int k0 = 0; k0 < K; k0 += BK) {
    for (int i = tid; i < BM * BK; i += 256) {
      int m = i / BK, k = i % BK;
      float v = 0.f;
      if (k0 + k < K) {
        v = A[(size_t)(bm + m) * K + k0 + k];
        if (scA) v = fmaf(v, scA[k0 + k], shA[k0 + k]);
      }
      As[k][m] = v;
    }
    for (int i = tid; i < BN * BK; i += 256) {
      int n = i / BK, k = i % BK;
      float v = 0.f;
      if (k0 + k < K) v = Bw[(size_t)(bn + n) * K + k0 + k];
      Bs[k][n] = v;
    }
    __syncthreads();
#pragma unroll
    for (int k = 0; k < BK; k++) {
      float a4[4], b4[4];
#pragma unroll
      for (int xx = 0; xx < 4; xx++) a4[xx] = As[k][tr * 4 + xx];
#pragma unroll
      for (int yy = 0; yy < 4; yy++) b4[yy] = Bs[k][tc * 4 + yy];
#pragma unroll
      for (int xx = 0; xx < 4; xx++)
#pragma unroll
        for (int yy = 0; yy < 4; yy++) acc[xx][yy] = fmaf(a4[xx], b4[yy], acc[xx][yy]);
    }
    __syncthreads();
  }
  for (int xx = 0; xx < 4; xx++) {
    int m = bm + tr * 4 + xx;
    for (int yy = 0; yy < 4; yy++) {
      int n = bn + tc * 4 + yy;
      float v = acc[xx][yy] + bias[n];
      if (RELU) v = fmaxf(v, 0.f);
      C[(size_t)m * Nn + n] = v;
    }
  }
}

__global__ __launch_bounds__(256) void colstats_kernel(const float* __restrict__ X, int M, int C,
                                                       float* __restrict__ sum, float* __restrict__ sumsq) {
  int cl = threadIdx.x & 63, rl = threadIdx.x >> 6;
  int c = blockIdx.x * 64 + cl;
  float s = 0.f, q = 0.f;
  int r0 = blockIdx.y * 256;
  int rend = min(r0 + 256, M);
  for (int r = r0 + rl; r < rend; r += 4) {
    float v = X[(size_t)r * C + c];
    s += v;
    q = fmaf(v, v, q);
  }
  __shared__ float ss[4][64];
  __shared__ float qq[4][64];
  ss[rl][cl] = s;
  qq[rl][cl] = q;
  __syncthreads();
  if (rl == 0) {
    s = ss[0][cl] + ss[1][cl] + ss[2][cl] + ss[3][cl];
    q = qq[0][cl] + qq[1][cl] + qq[2][cl] + qq[3][cl];
    atomicAdd(&sum[c], s);
    atomicAdd(&sumsq[c], q);
  }
}

__global__ __launch_bounds__(256) void colstats_bf16_kernel(const unsigned short* __restrict__ X, int M, int C,
                                                            float* __restrict__ sum, float* __restrict__ sumsq) {
  int cl = threadIdx.x & 63, rl = threadIdx.x >> 6;
  int c = blockIdx.x * 64 + cl;
  float s = 0.f, q = 0.f;
  int r0 = blockIdx.y * 256;
  int rend = min(r0 + 256, M);
  for (int r = r0 + rl; r < rend; r += 4) {
    unsigned int u = X[(size_t)r * C + c];
    float v;
    u <<= 16;
    v = *(float*)&u;
    s += v;
    q = fmaf(v, v, q);
  }
  __shared__ float ss[4][64];
  __shared__ float qq[4][64];
  ss[rl][cl] = s;
  qq[rl][cl] = q;
  __syncthreads();
  if (rl == 0) {
    s = ss[0][cl] + ss[1][cl] + ss[2][cl] + ss[3][cl];
    q = qq[0][cl] + qq[1][cl] + qq[2][cl] + qq[3][cl];
    atomicAdd(&sum[c], s);
    atomicAdd(&sumsq[c], q);
  }
}

__global__ __launch_bounds__(256) void bn_coef_kernel(const float* __restrict__ sum, const float* __restrict__ sumsq,
                                                      const float* __restrict__ g, const float* __restrict__ be,
                                                      float* __restrict__ a, float* __restrict__ b, int C, float invM) {
  int c = blockIdx.x * blockDim.x + threadIdx.x;
  if (c >= C) return;
  float mu = sum[c] * invM;
  float var = sumsq[c] * invM - mu * mu;
  float s = g[c] * rsqrtf(var + 1e-5f);
  a[c] = s;
  b[c] = be[c] - mu * s;
}

__global__ __launch_bounds__(256) void head_kernel(const float* __restrict__ pooled,
                                                   const float* __restrict__ m3, const float* __restrict__ a3,
                                                   const float* __restrict__ b3, const float* __restrict__ Wout,
                                                   const float* __restrict__ bout, float* __restrict__ out, int B) {
  int b = blockIdx.x * blockDim.x + threadIdx.x;
  if (b >= B) return;
  float acc = bout[0];
#pragma unroll
  for (int j = 0; j < 32; j++) acc = fmaf(pooled[(size_t)b * 32 + j], Wout[j], acc);
#pragma unroll
  for (int j = 0; j < 64; j++) acc = fmaf(fmaf(m3[(size_t)b * 64 + j], a3[j], b3[j]), Wout[32 + j], acc);
  out[b] = 1.f / (1.f + expf(-acc));
}

extern "C" void kernel_launch(void* const* d_in, const int* in_sizes, int n_in,
                              void* d_out, int out_size, void* d_ws, size_t ws_size,
                              hipStream_t stream) {
  const float* x = (const float*)d_in[0];
  const int* eidx = (const int*)d_in[1];
  const int* batch = (const int*)d_in[2];
  const float* xmord = (const float*)d_in[3];
  const float* Wl1 = (const float*)d_in[4];
  const float* bl1 = (const float*)d_in[5];
  const float* Wr1 = (const float*)d_in[6];
  const float* Wl2 = (const float*)d_in[7];
  const float* bl2 = (const float*)d_in[8];
  const float* Wr2 = (const float*)d_in[9];
  const float* Wl3 = (const float*)d_in[10];
  const float* bl3 = (const float*)d_in[11];
  const float* Wr3 = (const float*)d_in[12];
  const float* Wf1 = (const float*)d_in[13];
  const float* bf1 = (const float*)d_in[14];
  const float* g1 = (const float*)d_in[15];
  const float* be1 = (const float*)d_in[16];
  const float* Wf2 = (const float*)d_in[17];
  const float* bf2 = (const float*)d_in[18];
  const float* g2 = (const float*)d_in[19];
  const float* be2 = (const float*)d_in[20];
  const float* Wf3 = (const float*)d_in[21];
  const float* bf3 = (const float*)d_in[22];
  const float* g3 = (const float*)d_in[23];
  const float* be3 = (const float*)d_in[24];
  const float* Wout = (const float*)d_in[25];
  const float* bout = (const float*)d_in[26];
  float* out = (float*)d_out;

  const int N = in_sizes[2];
  const int E = in_sizes[1] / 2;
  const int B = in_sizes[3] / MORD;
  const int Kp1 = 896;
  const int NB = (N + 1023) / 1024;
  const int* src = eidx;
  const int* dst = eidx + E;

  char* ws = (char*)d_ws;
  size_t off_ = 0;
  auto alloc = [&](size_t bytes) { size_t o = off_; off_ += (bytes + 255) & ~(size_t)255; return o; };
  size_t oHX1 = alloc((size_t)N * 64 * 2);   // also H3 f32 [N][32] overlay (hx1 dead after T1)
  size_t oHX2 = alloc((size_t)N * 64 * 2);   // MLP overlay: Abf/Bbf1/W2p/b2p
  size_t oHX3 = alloc((size_t)N * 64 * 2);   // MLP overlay: m1/m2/m3
  size_t oDeg = alloc((size_t)N * 4);
  size_t oOff = alloc((size_t)(N + 1) * 4);
  size_t oCur = alloc((size_t)N * 4);
  size_t oCsr = alloc((size_t)E * 4);
  size_t oGoff = alloc((size_t)(B + 1) * 4);
  size_t oBsum = alloc(1024 * 4);
  size_t oPool = alloc((size_t)B * 32 * 4);
  size_t oStats = alloc(4096 * 4);
  size_t oWc1 = alloc(352 * 64 * 2);
  size_t oWc2 = alloc(352 * 64 * 2);
  size_t oWc3 = alloc(352 * 64 * 2);
  (void)ws_size;

  unsigned short* hx1 = (unsigned short*)(ws + oHX1);
  unsigned short* hx2 = (unsigned short*)(ws + oHX2);
  unsigned short* hx3 = (unsigned short*)(ws + oHX3);
  float* H3 = (float*)(ws + oHX1);  // overlay
  int* deg = (int*)(ws + oDeg);
  int* offp = (int*)(ws + oOff);
  int* cursor = (int*)(ws + oCur);
  int* csr = (int*)(ws + oCsr);
  int* goff = (int*)(ws + oGoff);
  int* bsum = (int*)(ws + oBsum);
  float* pooled = (float*)(ws + oPool);
  float* st = (float*)(ws + oStats);
  unsigned short* Wc1 = (unsigned short*)(ws + oWc1);
  unsigned short* Wc2 = (unsigned short*)(ws + oWc2);
  unsigned short* Wc3 = (unsigned short*)(ws + oWc3);
  float *s1 = st, *q1 = st + 512, *a1 = st + 1024, *h1 = st + 1536;
  float *s2 = st + 2048, *q2 = st + 2176, *a2 = st + 2304, *h2 = st + 2432;
  float *s3 = st + 2560, *q3 = st + 2624, *a3 = st + 2688, *h3 = st + 2752;

  // MLP overlays (stream-serialized): hx2 region free after T2, hx3 free after T3
  unsigned short* Abf = (unsigned short*)(ws + oHX2);
  unsigned short* Bbf1 = (unsigned short*)(ws + oHX2 + 29360128);
  unsigned short* W2p = (unsigned short*)(ws + oHX2 + 29360128 + 917504);
  float* b2p = (float*)(ws + oHX2 + 29360128 + 917504 + 131072);
  unsigned short* m1 = (unsigned short*)(ws + oHX3);
  float* m2 = (float*)(ws + oHX3 + 16777216);
  float* m3 = (float*)(ws + oHX3 + 25165824);

  hipMemsetAsync(deg, 0, (size_t)N * 4, stream);
  hipMemsetAsync(st, 0, 4096 * 4, stream);

  // CSR build + graph offsets
  deg_kernel<<<(E + 255) / 256, 256, 0, stream>>>(dst, deg, E);
  scan_block<<<NB, 256, 0, stream>>>(deg, bsum, N);
  scan_bsum<<<1, 1024, 0, stream>>>(bsum, NB);
  scan_write<<<NB, 256, 0, stream>>>(deg, bsum, offp, cursor, N, E);
  csr_fill<<<(E + 255) / 256, 256, 0, stream>>>(src, dst, cursor, csr, E);
  graph_off<<<(B + 1 + 255) / 256, 256, 0, stream>>>(batch, goff, N, B);

  // weight prep (tiny)
  prep_wcat<<<88, 256, 0, stream>>>(Wl1, Wr1, Wc1, 8);
  prep_wcat<<<88, 256, 0, stream>>>(Wl2, Wr2, Wc2, 32);
  prep_wcat<<<88, 256, 0, stream>>>(Wl3, Wr3, Wc3, 32);

  // GNN layers via MFMA all-degree transform
  prep_hx1<<<(N + 255) / 256, 256, 0, stream>>>(x, offp, csr, hx1, N);
  mfconv_mfma<1, 0><<<512, 512, 0, stream>>>(hx1, Wc1, bl1, offp, hx2, N);
  gather_bf16<<<(int)(((long long)N * 4 + 255) / 256), 256, 0, stream>>>(hx2, offp, csr, hx2, N);
  mfconv_mfma<2, 0><<<512, 512, 0, stream>>>(hx2, Wc2, bl2, offp, hx3, N);
  gather_bf16<<<(int)(((long long)N * 4 + 255) / 256), 256, 0, stream>>>(hx3, offp, csr, hx3, N);
  mfconv_mfma<2, 1><<<512, 512, 0, stream>>>(hx3, Wc3, bl3, offp, H3, N);

  pool_seg<<<(B * 64 + 255) / 256, 256, 0, stream>>>(H3, goff, pooled, B);

  // ---- MLP head (bf16 MFMA for fc1/fc2) ----
  cvt_bf16_pad<<<(B * (Kp1 / 4) + 255) / 256, 256, 0, stream>>>(xmord, Abf, B, MORD, Kp1);
  cvt_bf16_pad<<<(512 * (Kp1 / 4) + 255) / 256, 256, 0, stream>>>(Wf1, Bbf1, 512, MORD, Kp1);

  gemm_mfma<1><<<dim3(512 / 128, B / 128), 256, 0, stream>>>(Abf, Bbf1, bf1, m1, B, 512, Kp1);
  colstats_bf16_kernel<<<dim3(512 / 64, B / 256), 256, 0, stream>>>(m1, B, 512, s1, q1);
  bn_coef_kernel<<<2, 256, 0, stream>>>(s1, q1, g1, be1, a1, h1, 512, 1.f / B);

  prepW2_kernel<<<32, 256, 0, stream>>>(Wf2, bf2, a1, h1, W2p, b2p, 128, 512);
  gemm_mfma<0><<<dim3(128 / 128, B / 128), 256, 0, stream>>>(m1, W2p, b2p, m2, B, 128, 512);
  colstats_kernel<<<dim3(128 / 64, B / 256), 256, 0, stream>>>(m2, B, 128, s2, q2);
  bn_coef_kernel<<<1, 256, 0, stream>>>(s2, q2, g2, be2, a2, h2, 128, 1.f / B);

  gemm_bias<true><<<dim3(64 / 64, B / 64), 256, 0, stream>>>(m2, Wf3, bf3, a2, h2, m3, B, 64, 128);
  colstats_kernel<<<dim3(1, B / 256), 256, 0, stream>>>(m3, B, 64, s3, q3);
  bn_coef_kernel<<<1, 256, 0, stream>>>(s3, q3, g3, be3, a3, h3, 64, 1.f / B);

  head_kernel<<<(B + 255) / 256, 256, 0, stream>>>(pooled, m3, a3, h3, Wout, bout, out, B);
}

// Round 7
// 413.557 us; speedup vs baseline: 2.7193x; 1.1058x over previous
//
#include <hip/hip_runtime.h>
#include <hip/hip_bf16.h>
#include <math.h>

#define MORD 862

typedef short s16x8 __attribute__((ext_vector_type(8)));
typedef float f32x4 __attribute__((ext_vector_type(4)));

static __device__ __forceinline__ unsigned short f2bf(float v) {
  __hip_bfloat16 h = __float2bfloat16(v);
  return *(unsigned short*)&h;
}

// ---- Binned CSR build (dst>>10 bins; write-combined multisplit) ----
__global__ __launch_bounds__(256) void bin_hist(const int* __restrict__ dstA, int* __restrict__ bhist, int E, int nbins) {
  __shared__ int lh[512];
  for (int i = threadIdx.x; i < nbins; i += 256) lh[i] = 0;
  __syncthreads();
  for (int e = blockIdx.x * 256 + threadIdx.x; e < E; e += gridDim.x * 256)
    atomicAdd(&lh[dstA[e] >> 10], 1);
  __syncthreads();
  for (int i = threadIdx.x; i < nbins; i += 256)
    if (lh[i]) atomicAdd(&bhist[i], lh[i]);
}

__global__ __launch_bounds__(512) void bin_scan(const int* __restrict__ bhist, int* __restrict__ boff,
                                                int* __restrict__ gcur, int nbins, int E) {
  __shared__ int ts[512];
  int tid = threadIdx.x;
  int v = (tid < nbins) ? bhist[tid] : 0;
  ts[tid] = v;
  __syncthreads();
  for (int st = 1; st < 512; st <<= 1) {
    int t = (tid >= st) ? ts[tid - st] : 0;
    __syncthreads();
    ts[tid] += t;
    __syncthreads();
  }
  int ex = ts[tid] - v;
  if (tid < nbins) { boff[tid] = ex; gcur[tid] = ex; }
  if (tid == 0) boff[nbins] = E;
}

__global__ __launch_bounds__(256) void bin_split(const int* __restrict__ srcA, const int* __restrict__ dstA,
                                                 int* __restrict__ gcur, unsigned long long* __restrict__ ebuf,
                                                 int E, int nbins) {
  __shared__ unsigned long long sbuf[512 * 8];
  __shared__ int lcur[512];
  int tid = threadIdx.x;
  for (int base = blockIdx.x * 1024; base < E; base += (int)gridDim.x * 1024) {
    for (int i = tid; i < nbins; i += 256) lcur[i] = 0;
    __syncthreads();
    int e0 = base + tid * 4;
#pragma unroll
    for (int j = 0; j < 4; j++) {
      int e = e0 + j;
      if (e < E) {
        int d = dstA[e], s = srcA[e];
        int bin = d >> 10;
        unsigned long long p = ((unsigned long long)(unsigned int)d << 32) | (unsigned int)s;
        int slot = atomicAdd(&lcur[bin], 1);
        if (slot < 8) sbuf[bin * 8 + slot] = p;
        else { int g = atomicAdd(&gcur[bin], 1); ebuf[g] = p; }  // rare overflow
      }
    }
    __syncthreads();
    for (int b = tid; b < nbins; b += 256) {
      int cnt = min(lcur[b], 8);
      if (cnt > 0) {
        int g = atomicAdd(&gcur[b], cnt);
        for (int k = 0; k < cnt; k++) ebuf[g + k] = sbuf[b * 8 + k];
      }
    }
    __syncthreads();
  }
}

// one block per bin: local histogram+scan -> off[] coalesced; csr scatter confined to 8KB window
__global__ __launch_bounds__(256) void bin_csr(const unsigned long long* __restrict__ ebuf,
                                               const int* __restrict__ boff,
                                               int* __restrict__ off, int* __restrict__ csr,
                                               int N, int E) {
  __shared__ int lcur[1024];
  __shared__ int part[256];
  int b = blockIdx.x;
  int n0 = b << 10;
  int nn = min(1024, N - n0);
  int e0 = boff[b], e1 = boff[b + 1];
  int tid = threadIdx.x;
  for (int i = tid; i < nn; i += 256) lcur[i] = 0;
  __syncthreads();
  for (int e = e0 + tid; e < e1; e += 256) {
    int d = (int)(ebuf[e] >> 32);
    atomicAdd(&lcur[d - n0], 1);
  }
  __syncthreads();
  int base4 = tid * 4;
  int c0 = (base4 < nn) ? lcur[base4] : 0;
  int c1 = (base4 + 1 < nn) ? lcur[base4 + 1] : 0;
  int c2 = (base4 + 2 < nn) ? lcur[base4 + 2] : 0;
  int c3 = (base4 + 3 < nn) ? lcur[base4 + 3] : 0;
  int tot = c0 + c1 + c2 + c3;
  part[tid] = tot;
  __syncthreads();
  for (int st = 1; st < 256; st <<= 1) {
    int t = (tid >= st) ? part[tid - st] : 0;
    __syncthreads();
    part[tid] += t;
    __syncthreads();
  }
  int pre = part[tid] - tot;
  __syncthreads();
  if (base4 < nn)     { lcur[base4]     = pre;                off[n0 + base4]     = e0 + pre; }
  if (base4 + 1 < nn) { lcur[base4 + 1] = pre + c0;           off[n0 + base4 + 1] = e0 + pre + c0; }
  if (base4 + 2 < nn) { lcur[base4 + 2] = pre + c0 + c1;      off[n0 + base4 + 2] = e0 + pre + c0 + c1; }
  if (base4 + 3 < nn) { lcur[base4 + 3] = pre + c0 + c1 + c2; off[n0 + base4 + 3] = e0 + pre + c0 + c1 + c2; }
  if (b == 0 && tid == 0) off[N] = E;
  __syncthreads();
  for (int e = e0 + tid; e < e1; e += 256) {
    unsigned long long p = ebuf[e];
    int d = (int)(p >> 32);
    int s = (int)(p & 0xffffffffu);
    int slot = atomicAdd(&lcur[d - n0], 1);
    csr[e0 + slot] = s;
  }
}

__global__ __launch_bounds__(256) void graph_off(const int* __restrict__ batch, int* __restrict__ goff, int N, int B) {
  int b = blockIdx.x * blockDim.x + threadIdx.x;
  if (b > B) return;
  int lo = 0, hi = N;
  while (lo < hi) {
    int mid = (lo + hi) >> 1;
    if (batch[mid] < b) lo = mid + 1; else hi = mid;
  }
  goff[b] = lo;
}

// all three Wcat sets in one launch. Wcat[(d*32+o)][k]: k<CIN Wl, CIN<=k<2CIN Wr, else 0
__global__ __launch_bounds__(256) void prep_wcat3(const float* __restrict__ Wl1, const float* __restrict__ Wr1,
                                                  unsigned short* __restrict__ Wc1,
                                                  const float* __restrict__ Wl2, const float* __restrict__ Wr2,
                                                  unsigned short* __restrict__ Wc2,
                                                  const float* __restrict__ Wl3, const float* __restrict__ Wr3,
                                                  unsigned short* __restrict__ Wc3) {
  int set = blockIdx.y;
  const float* Wl = set == 0 ? Wl1 : (set == 1 ? Wl2 : Wl3);
  const float* Wr = set == 0 ? Wr1 : (set == 1 ? Wr2 : Wr3);
  unsigned short* Wc = set == 0 ? Wc1 : (set == 1 ? Wc2 : Wc3);
  int CIN = set == 0 ? 8 : 32;
  int idx = blockIdx.x * 256 + threadIdx.x;
  if (idx >= 352 * 64) return;
  int row = idx >> 6, k = idx & 63;
  int d = row >> 5, o = row & 31;
  float v = 0.f;
  if (k < CIN) v = Wl[((size_t)d * 32 + o) * CIN + k];
  else if (k < 2 * CIN) v = Wr[((size_t)d * 32 + o) * CIN + (k - CIN)];
  Wc[idx] = f2bf(v);
}

// hx1[n][64] bf16: 0-7 = neighbor-sum(x), 8-15 = x, rest zero
__global__ __launch_bounds__(256) void prep_hx1(const float* __restrict__ x, const int* __restrict__ off,
                                                const int* __restrict__ csr, unsigned short* __restrict__ hx1, int N) {
  int n = blockIdx.x * 256 + threadIdx.x;
  if (n >= N) return;
  int a = off[n], b = off[n + 1];
  float ag[8] = {};
  for (int j = a; j < b; j++) {
    const float* xr = x + (size_t)csr[j] * 8;
#pragma unroll
    for (int t = 0; t < 8; t++) ag[t] += xr[t];
  }
  const float* xo = x + (size_t)n * 8;
  unsigned short* d = hx1 + (size_t)n * 64;
  s16x8 w0, w1, z;
#pragma unroll
  for (int t = 0; t < 8; t++) {
    w0[t] = (short)f2bf(ag[t]);
    w1[t] = (short)f2bf(xo[t]);
    z[t] = 0;
  }
  *(s16x8*)(d) = w0;
  *(s16x8*)(d + 8) = w1;
  *(s16x8*)(d + 16) = z;
  *(s16x8*)(d + 24) = z;
  *(s16x8*)(d + 32) = z;
  *(s16x8*)(d + 40) = z;
  *(s16x8*)(d + 48) = z;
  *(s16x8*)(d + 56) = z;
}

// sum neighbors' x-half (cols 32-63) into own agg-half (cols 0-31). thread = (node, 8-ch chunk)
__global__ __launch_bounds__(256) void gather_bf16(const unsigned short* __restrict__ hx, const int* __restrict__ off,
                                                   const int* __restrict__ csr, unsigned short* __restrict__ hxw, int N) {
  long long tid = (long long)blockIdx.x * 256 + threadIdx.x;
  if (tid >= (long long)N * 4) return;
  int n = (int)(tid >> 2), q = (int)(tid & 3);
  int a = off[n], b = off[n + 1];
  float s[8] = {};
  for (int j = a; j < b; j++) {
    const s16x8 v = *(const s16x8*)(hx + (size_t)csr[j] * 64 + 32 + q * 8);
#pragma unroll
    for (int t = 0; t < 8; t++) {
      unsigned int u = ((unsigned int)(unsigned short)v[t]) << 16;
      s[t] += *(float*)&u;
    }
  }
  s16x8 w;
#pragma unroll
  for (int t = 0; t < 8; t++) w[t] = (short)f2bf(s[t]);
  *(s16x8*)(hxw + (size_t)n * 64 + q * 8) = w;
}

// MFMA all-degree transform: per 128-row tile, C[128x352] = A[128x64] @ Wcat[352x64]^T;
// epilogue selects the 32 cols matching each row's degree. XOR-swizzled LDS.
template <int KS, int OUTMODE>
__global__ __launch_bounds__(512, 4) void mfconv_mfma(const unsigned short* __restrict__ hx,
                                                      const unsigned short* __restrict__ Wcat,
                                                      const float* __restrict__ bl,
                                                      const int* __restrict__ off,
                                                      void* __restrict__ outp, int N) {
  __shared__ __align__(16) unsigned short As[128 * 64];
  __shared__ __align__(16) unsigned short Bs[352 * 64];
  __shared__ float sbias[352];
  __shared__ int sdeg[128];
  const int tid = threadIdx.x;
  const int wid = tid >> 6, lane = tid & 63;

  for (int s = wid; s < 44; s += 8) {
    int c = s * 64 + lane;
    int cs = c ^ ((c >> 3) & 7);
    __builtin_amdgcn_global_load_lds((const __attribute__((address_space(1))) void*)((const char*)Wcat + (size_t)cs * 16),
                                     (__attribute__((address_space(3))) void*)((char*)Bs + s * 1024), 16, 0, 0);
  }
  for (int i = tid; i < 352; i += 512) sbias[i] = bl[i];

  const int ntiles = N >> 7;
  for (int t = blockIdx.x; t < ntiles; t += (int)gridDim.x) {
    const int row0 = t << 7;
    __syncthreads();
    const char* Abase = (const char*)(hx + (size_t)row0 * 64);
    for (int s = wid; s < 16; s += 8) {
      int c = s * 64 + lane;
      int cs = c ^ ((c >> 3) & 7);
      __builtin_amdgcn_global_load_lds((const __attribute__((address_space(1))) void*)(Abase + (size_t)cs * 16),
                                       (__attribute__((address_space(3))) void*)((char*)As + s * 1024), 16, 0, 0);
    }
    if (tid < 128) sdeg[tid] = min(off[row0 + tid + 1] - off[row0 + tid], 10);
    __syncthreads();

    const int ra = wid * 16 + (lane & 15);
    const int g4 = lane >> 4;
    const int rl0 = wid * 16 + g4 * 4;
    int dj[4];
#pragma unroll
    for (int j = 0; j < 4; j++) dj[j] = sdeg[rl0 + j];

#pragma unroll
    for (int h = 0; h < 2; h++) {
      f32x4 acc[11] = {};
#pragma unroll
      for (int kk = 0; kk < KS; kk++) {
        int ca = ra * 8 + kk * 4 + g4;
        s16x8 af = *(const s16x8*)((const char*)As + (size_t)(ca ^ (ra & 7)) * 16);
#pragma unroll
        for (int nn = 0; nn < 11; nn++) {
          int rb = (h * 11 + nn) * 16 + (lane & 15);
          int cb = rb * 8 + kk * 4 + g4;
          s16x8 bf = *(const s16x8*)((const char*)Bs + (size_t)(cb ^ (rb & 7)) * 16);
          acc[nn] = __builtin_amdgcn_mfma_f32_16x16x32_bf16(af, bf, acc[nn], 0, 0, 0);
        }
      }
#pragma unroll
      for (int nn = 0; nn < 11; nn++) {
        int n = h * 11 + nn;
        int dsel = n >> 1;
        int o = (n & 1) * 16 + (lane & 15);
        float bv = sbias[dsel * 32 + o];
#pragma unroll
        for (int j = 0; j < 4; j++) {
          if (dj[j] == dsel) {
            float v = acc[nn][j] + bv;
            size_t gr = (size_t)row0 + rl0 + j;
            if (OUTMODE == 0) {
              v = fmaxf(v, 0.f);
              ((unsigned short*)outp)[gr * 64 + 32 + o] = f2bf(v);
            } else {
              ((float*)outp)[gr * 32 + o] = v;
            }
          }
        }
      }
    }
  }
}

// one wave per graph; writes mean directly (no atomics)
__global__ __launch_bounds__(256) void pool_seg(const float* __restrict__ h, const int* __restrict__ goff,
                                                float* __restrict__ pooled, int B) {
  int w = (int)((blockIdx.x * 256 + threadIdx.x) >> 6);
  if (w >= B) return;
  int lane = threadIdx.x & 63;
  int c = lane & 31, r2 = lane >> 5;
  int a = goff[w], b = goff[w + 1];
  float s = 0.f;
  for (int r = a + r2; r < b; r += 2) s += h[(size_t)r * 32 + c];
  s += __shfl_down(s, 32);
  if (r2 == 0) pooled[(size_t)w * 32 + c] = s / fmaxf((float)(b - a), 1.f);
}

// fp32 -> bf16 with K padding to Kp (zeros in pad)
__global__ __launch_bounds__(256) void cvt_bf16_pad(const float* __restrict__ src, unsigned short* __restrict__ dst,
                                                    int rows, int K, int Kp) {
  int t = blockIdx.x * blockDim.x + threadIdx.x;
  int q = Kp / 4;
  if (t >= rows * q) return;
  int r = t / q, c4 = (t % q) * 4;
#pragma unroll
  for (int j = 0; j < 4; j++) {
    int k = c4 + j;
    float v = (k < K) ? src[(size_t)r * K + k] : 0.f;
    dst[(size_t)r * Kp + k] = f2bf(v);
  }
}

__global__ __launch_bounds__(256) void prepW2_kernel(const float* __restrict__ W2, const float* __restrict__ b2,
                                                     const float* __restrict__ a1, const float* __restrict__ h1,
                                                     unsigned short* __restrict__ W2p, float* __restrict__ b2p,
                                                     int Nn, int K) {
  int wid = threadIdx.x >> 6, lane = threadIdx.x & 63;
  int n = blockIdx.x * 4 + wid;
  if (n >= Nn) return;
  float part = 0.f;
  for (int k = lane; k < K; k += 64) {
    float w = W2[(size_t)n * K + k];
    W2p[(size_t)n * K + k] = f2bf(w * a1[k]);
    part = fmaf(w, h1[k], part);
  }
#pragma unroll
  for (int off = 32; off > 0; off >>= 1) part += __shfl_down(part, off, 64);
  if (lane == 0) b2p[n] = b2[n] + part;
}

// bf16 MFMA GEMM: C[M,Nn] = relu(A[M,Kp] @ Bw[Nn,Kp]^T + bias). 128x128 tile, BK=64.
template <int OUTBF16>
__global__ __launch_bounds__(256) void gemm_mfma(const unsigned short* __restrict__ A,
                                                 const unsigned short* __restrict__ Bw,
                                                 const float* __restrict__ bias,
                                                 void* __restrict__ Cout, int M, int Nn, int Kp) {
  __shared__ __align__(16) unsigned short As[128 * 64];
  __shared__ __align__(16) unsigned short Bs[128 * 64];
  int tid = threadIdx.x;
  int wid = tid >> 6, lane = tid & 63;
  int m0 = blockIdx.y * 128, n0 = blockIdx.x * 128;
  int wr = wid >> 1, wc = wid & 1;
  f32x4 acc[4][4] = {};

  int srow_l = lane >> 3;
  int scol = (lane & 7) * 8;
  int aReadBase = ((wr * 64 + (lane & 15)) * 128) + ((lane >> 4) * 16);
  int bReadBase = ((wc * 64 + (lane & 15)) * 128) + ((lane >> 4) * 16);

  const unsigned short* Ablk = A + (size_t)m0 * Kp;
  const unsigned short* Bblk = Bw + (size_t)n0 * Kp;

  for (int k0 = 0; k0 < Kp; k0 += 64) {
#pragma unroll
    for (int i = 0; i < 4; i++) {
      int s = wid * 4 + i;
      int row = s * 8 + srow_l;
      const unsigned short* ga = Ablk + (size_t)row * Kp + k0 + scol;
      const unsigned short* gb = Bblk + (size_t)row * Kp + k0 + scol;
      __builtin_amdgcn_global_load_lds((const __attribute__((address_space(1))) void*)ga,
                                       (__attribute__((address_space(3))) void*)(As + s * 512), 16, 0, 0);
      __builtin_amdgcn_global_load_lds((const __attribute__((address_space(1))) void*)gb,
                                       (__attribute__((address_space(3))) void*)(Bs + s * 512), 16, 0, 0);
    }
    __syncthreads();
#pragma unroll
    for (int kk = 0; kk < 2; kk++) {
      s16x8 af[4], bfr[4];
#pragma unroll
      for (int m = 0; m < 4; m++)
        af[m] = *(const s16x8*)((const char*)As + aReadBase + m * (16 * 128) + kk * 64);
#pragma unroll
      for (int n = 0; n < 4; n++)
        bfr[n] = *(const s16x8*)((const char*)Bs + bReadBase + n * (16 * 128) + kk * 64);
#pragma unroll
      for (int m = 0; m < 4; m++)
#pragma unroll
        for (int n = 0; n < 4; n++)
          acc[m][n] = __builtin_amdgcn_mfma_f32_16x16x32_bf16(af[m], bfr[n], acc[m][n], 0, 0, 0);
    }
    __syncthreads();
  }

  int rbase = m0 + wr * 64 + (lane >> 4) * 4;
  int cbase = n0 + wc * 64 + (lane & 15);
#pragma unroll
  for (int m = 0; m < 4; m++)
#pragma unroll
    for (int n = 0; n < 4; n++) {
      int col = cbase + n * 16;
      float bv = bias[col];
#pragma unroll
      for (int j = 0; j < 4; j++) {
        int row = rbase + m * 16 + j;
        float v = fmaxf(acc[m][n][j] + bv, 0.f);
        if (OUTBF16)
          ((unsigned short*)Cout)[(size_t)row * Nn + col] = f2bf(v);
        else
          ((float*)Cout)[(size_t)row * Nn + col] = v;
      }
    }
}

// fp32 fallback GEMM (used for fc3)
template <bool RELU>
__global__ __launch_bounds__(256) void gemm_bias(const float* __restrict__ A, const float* __restrict__ Bw,
                                                 const float* __restrict__ bias,
                                                 const float* __restrict__ scA, const float* __restrict__ shA,
                                                 float* __restrict__ C, int M, int Nn, int K) {
  const int BM = 64, BN = 64, BK = 16;
  __shared__ float As[BK][BM + 1];
  __shared__ float Bs[BK][BN + 1];
  int bm = blockIdx.y * BM, bn = blockIdx.x * BN;
  int tid = threadIdx.x;
  int tr = tid / 16, tc = tid % 16;
  float acc[4][4] = {};
  for (int k0 = 0; k0 < K; k0 += BK) {
    for (int i = tid; i < BM * BK; i += 256) {
      int m = i / BK, k = i % BK;
      float v = 0.f;
      if (k0 + k < K) {
        v = A[(size_t)(bm + m) * K + k0 + k];
        if (scA) v = fmaf(v, scA[k0 + k], shA[k0 + k]);
      }
      As[k][m] = v;
    }
    for (int i = tid; i < BN * BK; i += 256) {
      int n = i / BK, k = i % BK;
      float v = 0.f;
      if (k0 + k < K) v = Bw[(size_t)(bn + n) * K + k0 + k];
      Bs[k][n] = v;
    }
    __syncthreads();
#pragma unroll
    for (int k = 0; k < BK; k++) {
      float a4[4], b4[4];
#pragma unroll
      for (int xx = 0; xx < 4; xx++) a4[xx] = As[k][tr * 4 + xx];
#pragma unroll
      for (int yy = 0; yy < 4; yy++) b4[yy] = Bs[k][tc * 4 + yy];
#pragma unroll
      for (int xx = 0; xx < 4; xx++)
#pragma unroll
        for (int yy = 0; yy < 4; yy++) acc[xx][yy] = fmaf(a4[xx], b4[yy], acc[xx][yy]);
    }
    __syncthreads();
  }
  for (int xx = 0; xx < 4; xx++) {
    int m = bm + tr * 4 + xx;
    for (int yy = 0; yy < 4; yy++) {
      int n = bn + tc * 4 + yy;
      float v = acc[xx][yy] + bias[n];
      if (RELU) v = fmaxf(v, 0.f);
      C[(size_t)m * Nn + n] = v;
    }
  }
}

__global__ __launch_bounds__(256) void colstats_kernel(const float* __restrict__ X, int M, int C,
                                                       float* __restrict__ sum, float* __restrict__ sumsq) {
  int cl = threadIdx.x & 63, rl = threadIdx.x >> 6;
  int c = blockIdx.x * 64 + cl;
  float s = 0.f, q = 0.f;
  int r0 = blockIdx.y * 256;
  int rend = min(r0 + 256, M);
  for (int r = r0 + rl; r < rend; r += 4) {
    float v = X[(size_t)r * C + c];
    s += v;
    q = fmaf(v, v, q);
  }
  __shared__ float ss[4][64];
  __shared__ float qq[4][64];
  ss[rl][cl] = s;
  qq[rl][cl] = q;
  __syncthreads();
  if (rl == 0) {
    s = ss[0][cl] + ss[1][cl] + ss[2][cl] + ss[3][cl];
    q = qq[0][cl] + qq[1][cl] + qq[2][cl] + qq[3][cl];
    atomicAdd(&sum[c], s);
    atomicAdd(&sumsq[c], q);
  }
}

__global__ __launch_bounds__(256) void colstats_bf16_kernel(const unsigned short* __restrict__ X, int M, int C,
                                                            float* __restrict__ sum, float* __restrict__ sumsq) {
  int cl = threadIdx.x & 63, rl = threadIdx.x >> 6;
  int c = blockIdx.x * 64 + cl;
  float s = 0.f, q = 0.f;
  int r0 = blockIdx.y * 256;
  int rend = min(r0 + 256, M);
  for (int r = r0 + rl; r < rend; r += 4) {
    unsigned int u = X[(size_t)r * C + c];
    float v;
    u <<= 16;
    v = *(float*)&u;
    s += v;
    q = fmaf(v, v, q);
  }
  __shared__ float ss[4][64];
  __shared__ float qq[4][64];
  ss[rl][cl] = s;
  qq[rl][cl] = q;
  __syncthreads();
  if (rl == 0) {
    s = ss[0][cl] + ss[1][cl] + ss[2][cl] + ss[3][cl];
    q = qq[0][cl] + qq[1][cl] + qq[2][cl] + qq[3][cl];
    atomicAdd(&sum[c], s);
    atomicAdd(&sumsq[c], q);
  }
}

__global__ __launch_bounds__(256) void bn_coef_kernel(const float* __restrict__ sum, const float* __restrict__ sumsq,
                                                      const float* __restrict__ g, const float* __restrict__ be,
                                                      float* __restrict__ a, float* __restrict__ b, int C, float invM) {
  int c = blockIdx.x * blockDim.x + threadIdx.x;
  if (c >= C) return;
  float mu = sum[c] * invM;
  float var = sumsq[c] * invM - mu * mu;
  float s = g[c] * rsqrtf(var + 1e-5f);
  a[c] = s;
  b[c] = be[c] - mu * s;
}

__global__ __launch_bounds__(256) void head_kernel(const float* __restrict__ pooled,
                                                   const float* __restrict__ m3, const float* __restrict__ a3,
                                                   const float* __restrict__ b3, const float* __restrict__ Wout,
                                                   const float* __restrict__ bout, float* __restrict__ out, int B) {
  int b = blockIdx.x * blockDim.x + threadIdx.x;
  if (b >= B) return;
  float acc = bout[0];
#pragma unroll
  for (int j = 0; j < 32; j++) acc = fmaf(pooled[(size_t)b * 32 + j], Wout[j], acc);
#pragma unroll
  for (int j = 0; j < 64; j++) acc = fmaf(fmaf(m3[(size_t)b * 64 + j], a3[j], b3[j]), Wout[32 + j], acc);
  out[b] = 1.f / (1.f + expf(-acc));
}

extern "C" void kernel_launch(void* const* d_in, const int* in_sizes, int n_in,
                              void* d_out, int out_size, void* d_ws, size_t ws_size,
                              hipStream_t stream) {
  const float* x = (const float*)d_in[0];
  const int* eidx = (const int*)d_in[1];
  const int* batch = (const int*)d_in[2];
  const float* xmord = (const float*)d_in[3];
  const float* Wl1 = (const float*)d_in[4];
  const float* bl1 = (const float*)d_in[5];
  const float* Wr1 = (const float*)d_in[6];
  const float* Wl2 = (const float*)d_in[7];
  const float* bl2 = (const float*)d_in[8];
  const float* Wr2 = (const float*)d_in[9];
  const float* Wl3 = (const float*)d_in[10];
  const float* bl3 = (const float*)d_in[11];
  const float* Wr3 = (const float*)d_in[12];
  const float* Wf1 = (const float*)d_in[13];
  const float* bf1 = (const float*)d_in[14];
  const float* g1 = (const float*)d_in[15];
  const float* be1 = (const float*)d_in[16];
  const float* Wf2 = (const float*)d_in[17];
  const float* bf2 = (const float*)d_in[18];
  const float* g2 = (const float*)d_in[19];
  const float* be2 = (const float*)d_in[20];
  const float* Wf3 = (const float*)d_in[21];
  const float* bf3 = (const float*)d_in[22];
  const float* g3 = (const float*)d_in[23];
  const float* be3 = (const float*)d_in[24];
  const float* Wout = (const float*)d_in[25];
  const float* bout = (const float*)d_in[26];
  float* out = (float*)d_out;

  const int N = in_sizes[2];
  const int E = in_sizes[1] / 2;
  const int B = in_sizes[3] / MORD;
  const int Kp1 = 896;
  const int nbins = (N + 1023) >> 10;
  const int* src = eidx;
  const int* dst = eidx + E;

  char* ws = (char*)d_ws;
  size_t off_ = 0;
  auto alloc = [&](size_t bytes) { size_t o = off_; off_ += (bytes + 255) & ~(size_t)255; return o; };
  size_t oHX1 = alloc((size_t)N * 64 * 2);   // also H3 f32 [N][32] overlay
  size_t oHX2 = alloc((size_t)N * 64 * 2);   // MLP overlay: Abf/Bbf1/W2p/b2p
  size_t oHX3 = alloc((size_t)N * 64 * 2);   // MLP overlay: m1/m2/m3
  size_t oOff = alloc((size_t)(N + 1) * 4);
  size_t oCsr = alloc((size_t)E * 4);
  size_t oEbuf = alloc((size_t)E * 8);
  size_t oGoff = alloc((size_t)(B + 1) * 4);
  size_t oPool = alloc((size_t)B * 32 * 4);
  size_t oStats = alloc(4096 * 4);
  size_t oBhist = alloc(512 * 4);
  size_t oBoff = alloc(513 * 4);
  size_t oGcur = alloc(512 * 4);
  size_t oWc1 = alloc(352 * 64 * 2);
  size_t oWc2 = alloc(352 * 64 * 2);
  size_t oWc3 = alloc(352 * 64 * 2);
  (void)ws_size;

  unsigned short* hx1 = (unsigned short*)(ws + oHX1);
  unsigned short* hx2 = (unsigned short*)(ws + oHX2);
  unsigned short* hx3 = (unsigned short*)(ws + oHX3);
  float* H3 = (float*)(ws + oHX1);  // overlay
  int* offp = (int*)(ws + oOff);
  int* csr = (int*)(ws + oCsr);
  unsigned long long* ebuf = (unsigned long long*)(ws + oEbuf);
  int* goff = (int*)(ws + oGoff);
  float* pooled = (float*)(ws + oPool);
  float* st = (float*)(ws + oStats);
  int* bhist = (int*)(ws + oBhist);
  int* boff = (int*)(ws + oBoff);
  int* gcur = (int*)(ws + oGcur);
  unsigned short* Wc1 = (unsigned short*)(ws + oWc1);
  unsigned short* Wc2 = (unsigned short*)(ws + oWc2);
  unsigned short* Wc3 = (unsigned short*)(ws + oWc3);
  float *s1 = st, *q1 = st + 512, *a1 = st + 1024, *h1 = st + 1536;
  float *s2 = st + 2048, *q2 = st + 2176, *a2 = st + 2304, *h2 = st + 2432;
  float *s3 = st + 2560, *q3 = st + 2624, *a3 = st + 2688, *h3 = st + 2752;

  // MLP overlays (stream-serialized lifetimes)
  unsigned short* Abf = (unsigned short*)(ws + oHX2);
  unsigned short* Bbf1 = (unsigned short*)(ws + oHX2 + 29360128);
  unsigned short* W2p = (unsigned short*)(ws + oHX2 + 29360128 + 917504);
  float* b2p = (float*)(ws + oHX2 + 29360128 + 917504 + 131072);
  unsigned short* m1 = (unsigned short*)(ws + oHX3);
  float* m2 = (float*)(ws + oHX3 + 16777216);
  float* m3 = (float*)(ws + oHX3 + 25165824);

  hipMemsetAsync(bhist, 0, 512 * 4, stream);
  hipMemsetAsync(st, 0, 4096 * 4, stream);

  // Binned CSR build
  bin_hist<<<400, 256, 0, stream>>>(dst, bhist, E, nbins);
  bin_scan<<<1, 512, 0, stream>>>(bhist, boff, gcur, nbins, E);
  bin_split<<<400, 256, 0, stream>>>(src, dst, gcur, ebuf, E, nbins);
  bin_csr<<<nbins, 256, 0, stream>>>(ebuf, boff, offp, csr, N, E);
  graph_off<<<(B + 1 + 255) / 256, 256, 0, stream>>>(batch, goff, N, B);

  // weight prep (one launch)
  prep_wcat3<<<dim3(88, 3), 256, 0, stream>>>(Wl1, Wr1, Wc1, Wl2, Wr2, Wc2, Wl3, Wr3, Wc3);

  // GNN layers via MFMA all-degree transform
  prep_hx1<<<(N + 255) / 256, 256, 0, stream>>>(x, offp, csr, hx1, N);
  mfconv_mfma<1, 0><<<512, 512, 0, stream>>>(hx1, Wc1, bl1, offp, hx2, N);
  gather_bf16<<<(int)(((long long)N * 4 + 255) / 256), 256, 0, stream>>>(hx2, offp, csr, hx2, N);
  mfconv_mfma<2, 0><<<512, 512, 0, stream>>>(hx2, Wc2, bl2, offp, hx3, N);
  gather_bf16<<<(int)(((long long)N * 4 + 255) / 256), 256, 0, stream>>>(hx3, offp, csr, hx3, N);
  mfconv_mfma<2, 1><<<512, 512, 0, stream>>>(hx3, Wc3, bl3, offp, H3, N);

  pool_seg<<<(B * 64 + 255) / 256, 256, 0, stream>>>(H3, goff, pooled, B);

  // ---- MLP head (bf16 MFMA for fc1/fc2) ----
  cvt_bf16_pad<<<(B * (Kp1 / 4) + 255) / 256, 256, 0, stream>>>(xmord, Abf, B, MORD, Kp1);
  cvt_bf16_pad<<<(512 * (Kp1 / 4) + 255) / 256, 256, 0, stream>>>(Wf1, Bbf1, 512, MORD, Kp1);

  gemm_mfma<1><<<dim3(512 / 128, B / 128), 256, 0, stream>>>(Abf, Bbf1, bf1, m1, B, 512, Kp1);
  colstats_bf16_kernel<<<dim3(512 / 64, B / 256), 256, 0, stream>>>(m1, B, 512, s1, q1);
  bn_coef_kernel<<<2, 256, 0, stream>>>(s1, q1, g1, be1, a1, h1, 512, 1.f / B);

  prepW2_kernel<<<32, 256, 0, stream>>>(Wf2, bf2, a1, h1, W2p, b2p, 128, 512);
  gemm_mfma<0><<<dim3(128 / 128, B / 128), 256, 0, stream>>>(m1, W2p, b2p, m2, B, 128, 512);
  colstats_kernel<<<dim3(128 / 64, B / 256), 256, 0, stream>>>(m2, B, 128, s2, q2);
  bn_coef_kernel<<<1, 256, 0, stream>>>(s2, q2, g2, be2, a2, h2, 128, 1.f / B);

  gemm_bias<true><<<dim3(64 / 64, B / 64), 256, 0, stream>>>(m2, Wf3, bf3, a2, h2, m3, B, 64, 128);
  colstats_kernel<<<dim3(1, B / 256), 256, 0, stream>>>(m3, B, 64, s3, q3);
  bn_coef_kernel<<<1, 256, 0, stream>>>(s3, q3, g3, be3, a3, h3, 64, 1.f / B);

  head_kernel<<<(B + 255) / 256, 256, 0, stream>>>(pooled, m3, a3, h3, Wout, bout, out, B);
}

// Round 8
// 393.356 us; speedup vs baseline: 2.8590x; 1.0514x over previous
//
#include <hip/hip_runtime.h>
#include <hip/hip_bf16.h>
#include <math.h>

#define MORD 862

typedef short s16x8 __attribute__((ext_vector_type(8)));
typedef float f32x4 __attribute__((ext_vector_type(4)));
typedef float f32x4a __attribute__((ext_vector_type(4), aligned(4)));

static __device__ __forceinline__ unsigned short f2bf(float v) {
  __hip_bfloat16 h = __float2bfloat16(v);
  return *(unsigned short*)&h;
}

// ---- Binned CSR build (dst>>10 bins; write-combined multisplit) ----
__global__ __launch_bounds__(256) void bin_hist(const int* __restrict__ dstA, int* __restrict__ bhist, int E, int nbins) {
  __shared__ int lh[512];
  for (int i = threadIdx.x; i < nbins; i += 256) lh[i] = 0;
  __syncthreads();
  for (int e = blockIdx.x * 256 + threadIdx.x; e < E; e += gridDim.x * 256)
    atomicAdd(&lh[dstA[e] >> 10], 1);
  __syncthreads();
  for (int i = threadIdx.x; i < nbins; i += 256)
    if (lh[i]) atomicAdd(&bhist[i], lh[i]);
}

__global__ __launch_bounds__(512) void bin_scan(const int* __restrict__ bhist, int* __restrict__ boff,
                                                int* __restrict__ gcur, int nbins, int E) {
  __shared__ int ts[512];
  int tid = threadIdx.x;
  int v = (tid < nbins) ? bhist[tid] : 0;
  ts[tid] = v;
  __syncthreads();
  for (int st = 1; st < 512; st <<= 1) {
    int t = (tid >= st) ? ts[tid - st] : 0;
    __syncthreads();
    ts[tid] += t;
    __syncthreads();
  }
  int ex = ts[tid] - v;
  if (tid < nbins) { boff[tid] = ex; gcur[tid] = ex; }
  if (tid == 0) boff[nbins] = E;
}

__global__ __launch_bounds__(256) void bin_split(const int* __restrict__ srcA, const int* __restrict__ dstA,
                                                 int* __restrict__ gcur, unsigned long long* __restrict__ ebuf,
                                                 int E, int nbins) {
  __shared__ unsigned long long sbuf[512 * 8];
  __shared__ int lcur[512];
  int tid = threadIdx.x;
  for (int base = blockIdx.x * 1024; base < E; base += (int)gridDim.x * 1024) {
    for (int i = tid; i < nbins; i += 256) lcur[i] = 0;
    __syncthreads();
    int e0 = base + tid * 4;
#pragma unroll
    for (int j = 0; j < 4; j++) {
      int e = e0 + j;
      if (e < E) {
        int d = dstA[e], s = srcA[e];
        int bin = d >> 10;
        unsigned long long p = ((unsigned long long)(unsigned int)d << 32) | (unsigned int)s;
        int slot = atomicAdd(&lcur[bin], 1);
        if (slot < 8) sbuf[bin * 8 + slot] = p;
        else { int g = atomicAdd(&gcur[bin], 1); ebuf[g] = p; }
      }
    }
    __syncthreads();
    for (int b = tid; b < nbins; b += 256) {
      int cnt = min(lcur[b], 8);
      if (cnt > 0) {
        int g = atomicAdd(&gcur[b], cnt);
        for (int k = 0; k < cnt; k++) ebuf[g + k] = sbuf[b * 8 + k];
      }
    }
    __syncthreads();
  }
}

__global__ __launch_bounds__(256) void bin_csr(const unsigned long long* __restrict__ ebuf,
                                               const int* __restrict__ boff,
                                               int* __restrict__ off, int* __restrict__ csr,
                                               int N, int E) {
  __shared__ int lcur[1024];
  __shared__ int part[256];
  int b = blockIdx.x;
  int n0 = b << 10;
  int nn = min(1024, N - n0);
  int e0 = boff[b], e1 = boff[b + 1];
  int tid = threadIdx.x;
  for (int i = tid; i < nn; i += 256) lcur[i] = 0;
  __syncthreads();
  for (int e = e0 + tid; e < e1; e += 256) {
    int d = (int)(ebuf[e] >> 32);
    atomicAdd(&lcur[d - n0], 1);
  }
  __syncthreads();
  int base4 = tid * 4;
  int c0 = (base4 < nn) ? lcur[base4] : 0;
  int c1 = (base4 + 1 < nn) ? lcur[base4 + 1] : 0;
  int c2 = (base4 + 2 < nn) ? lcur[base4 + 2] : 0;
  int c3 = (base4 + 3 < nn) ? lcur[base4 + 3] : 0;
  int tot = c0 + c1 + c2 + c3;
  part[tid] = tot;
  __syncthreads();
  for (int st = 1; st < 256; st <<= 1) {
    int t = (tid >= st) ? part[tid - st] : 0;
    __syncthreads();
    part[tid] += t;
    __syncthreads();
  }
  int pre = part[tid] - tot;
  __syncthreads();
  if (base4 < nn)     { lcur[base4]     = pre;                off[n0 + base4]     = e0 + pre; }
  if (base4 + 1 < nn) { lcur[base4 + 1] = pre + c0;           off[n0 + base4 + 1] = e0 + pre + c0; }
  if (base4 + 2 < nn) { lcur[base4 + 2] = pre + c0 + c1;      off[n0 + base4 + 2] = e0 + pre + c0 + c1; }
  if (base4 + 3 < nn) { lcur[base4 + 3] = pre + c0 + c1 + c2; off[n0 + base4 + 3] = e0 + pre + c0 + c1 + c2; }
  if (b == 0 && tid == 0) off[N] = E;
  __syncthreads();
  for (int e = e0 + tid; e < e1; e += 256) {
    unsigned long long p = ebuf[e];
    int d = (int)(p >> 32);
    int s = (int)(p & 0xffffffffu);
    int slot = atomicAdd(&lcur[d - n0], 1);
    csr[e0 + slot] = s;
  }
}

__global__ __launch_bounds__(256) void graph_off(const int* __restrict__ batch, int* __restrict__ goff, int N, int B) {
  int b = blockIdx.x * blockDim.x + threadIdx.x;
  if (b > B) return;
  int lo = 0, hi = N;
  while (lo < hi) {
    int mid = (lo + hi) >> 1;
    if (batch[mid] < b) lo = mid + 1; else hi = mid;
  }
  goff[b] = lo;
}

__global__ __launch_bounds__(256) void prep_wcat3(const float* __restrict__ Wl1, const float* __restrict__ Wr1,
                                                  unsigned short* __restrict__ Wc1,
                                                  const float* __restrict__ Wl2, const float* __restrict__ Wr2,
                                                  unsigned short* __restrict__ Wc2,
                                                  const float* __restrict__ Wl3, const float* __restrict__ Wr3,
                                                  unsigned short* __restrict__ Wc3) {
  int set = blockIdx.y;
  const float* Wl = set == 0 ? Wl1 : (set == 1 ? Wl2 : Wl3);
  const float* Wr = set == 0 ? Wr1 : (set == 1 ? Wr2 : Wr3);
  unsigned short* Wc = set == 0 ? Wc1 : (set == 1 ? Wc2 : Wc3);
  int CIN = set == 0 ? 8 : 32;
  int idx = blockIdx.x * 256 + threadIdx.x;
  if (idx >= 352 * 64) return;
  int row = idx >> 6, k = idx & 63;
  int d = row >> 5, o = row & 31;
  float v = 0.f;
  if (k < CIN) v = Wl[((size_t)d * 32 + o) * CIN + k];
  else if (k < 2 * CIN) v = Wr[((size_t)d * 32 + o) * CIN + (k - CIN)];
  Wc[idx] = f2bf(v);
}

// hx1[n][32] bf16: 0-7 = neighbor-sum(x), 8-15 = x, 16-31 zero
__global__ __launch_bounds__(256) void prep_hx1(const float* __restrict__ x, const int* __restrict__ off,
                                                const int* __restrict__ csr, unsigned short* __restrict__ hx1, int N) {
  int n = blockIdx.x * 256 + threadIdx.x;
  if (n >= N) return;
  int a = off[n], b = off[n + 1];
  float ag[8] = {};
  for (int j = a; j < b; j++) {
    const float* xr = x + (size_t)csr[j] * 8;
#pragma unroll
    for (int t = 0; t < 8; t++) ag[t] += xr[t];
  }
  const float* xo = x + (size_t)n * 8;
  unsigned short* d = hx1 + (size_t)n * 32;
  s16x8 w0, w1, z;
#pragma unroll
  for (int t = 0; t < 8; t++) {
    w0[t] = (short)f2bf(ag[t]);
    w1[t] = (short)f2bf(xo[t]);
    z[t] = 0;
  }
  *(s16x8*)(d) = w0;
  *(s16x8*)(d + 8) = w1;
  *(s16x8*)(d + 16) = z;
  *(s16x8*)(d + 24) = z;
}

// sum neighbors' x-half (cols 32-63) into own agg-half (cols 0-31)
__global__ __launch_bounds__(256) void gather_bf16(const unsigned short* __restrict__ hx, const int* __restrict__ off,
                                                   const int* __restrict__ csr, unsigned short* __restrict__ hxw, int N) {
  long long tid = (long long)blockIdx.x * 256 + threadIdx.x;
  if (tid >= (long long)N * 4) return;
  int n = (int)(tid >> 2), q = (int)(tid & 3);
  int a = off[n], b = off[n + 1];
  float s[8] = {};
  for (int j = a; j < b; j++) {
    const s16x8 v = *(const s16x8*)(hx + (size_t)csr[j] * 64 + 32 + q * 8);
#pragma unroll
    for (int t = 0; t < 8; t++) {
      unsigned int u = ((unsigned int)(unsigned short)v[t]) << 16;
      s[t] += *(float*)&u;
    }
  }
  s16x8 w;
#pragma unroll
  for (int t = 0; t < 8; t++) w[t] = (short)f2bf(s[t]);
  *(s16x8*)(hxw + (size_t)n * 64 + q * 8) = w;
}

// MFMA all-degree transform. ACH = 16B chunks per A row (4 -> 32-col rows, 8 -> 64-col rows).
template <int KS, int ACH, int OUTMODE>
__global__ __launch_bounds__(512, 4) void mfconv_mfma(const unsigned short* __restrict__ hx,
                                                      const unsigned short* __restrict__ Wcat,
                                                      const float* __restrict__ bl,
                                                      const int* __restrict__ off,
                                                      void* __restrict__ outp, int N) {
  __shared__ __align__(16) unsigned short As[128 * ACH * 8];
  __shared__ __align__(16) unsigned short Bs[352 * 64];
  __shared__ float sbias[352];
  __shared__ int sdeg[128];
  const int tid = threadIdx.x;
  const int wid = tid >> 6, lane = tid & 63;

  for (int s = wid; s < 44; s += 8) {
    int c = s * 64 + lane;
    int cs = c ^ ((c >> 3) & 7);
    __builtin_amdgcn_global_load_lds((const __attribute__((address_space(1))) void*)((const char*)Wcat + (size_t)cs * 16),
                                     (__attribute__((address_space(3))) void*)((char*)Bs + s * 1024), 16, 0, 0);
  }
  for (int i = tid; i < 352; i += 512) sbias[i] = bl[i];

  const int ntiles = N >> 7;
  for (int t = blockIdx.x; t < ntiles; t += (int)gridDim.x) {
    const int row0 = t << 7;
    __syncthreads();
    const char* Abase = (const char*)hx + (size_t)row0 * ACH * 16;
    for (int s = wid; s < 2 * ACH; s += 8) {
      int c = s * 64 + lane;
      int row = c / ACH, ch = c & (ACH - 1);
      int cs = row * ACH + (ch ^ (row & (ACH - 1)));
      __builtin_amdgcn_global_load_lds((const __attribute__((address_space(1))) void*)(Abase + (size_t)cs * 16),
                                       (__attribute__((address_space(3))) void*)((char*)As + s * 1024), 16, 0, 0);
    }
    if (tid < 128) sdeg[tid] = min(off[row0 + tid + 1] - off[row0 + tid], 10);
    __syncthreads();

    const int ra = wid * 16 + (lane & 15);
    const int g4 = lane >> 4;
    const int rl0 = wid * 16 + g4 * 4;
    int dj[4];
#pragma unroll
    for (int j = 0; j < 4; j++) dj[j] = sdeg[rl0 + j];

#pragma unroll
    for (int h = 0; h < 2; h++) {
      f32x4 acc[11] = {};
#pragma unroll
      for (int kk = 0; kk < KS; kk++) {
        int cha = (kk * 4 + g4) ^ (ra & (ACH - 1));
        s16x8 af = *(const s16x8*)((const char*)As + (size_t)(ra * ACH + cha) * 16);
#pragma unroll
        for (int nn = 0; nn < 11; nn++) {
          int rb = (h * 11 + nn) * 16 + (lane & 15);
          int cb = rb * 8 + kk * 4 + g4;
          s16x8 bf = *(const s16x8*)((const char*)Bs + (size_t)(cb ^ (rb & 7)) * 16);
          acc[nn] = __builtin_amdgcn_mfma_f32_16x16x32_bf16(af, bf, acc[nn], 0, 0, 0);
        }
      }
#pragma unroll
      for (int nn = 0; nn < 11; nn++) {
        int n = h * 11 + nn;
        int dsel = n >> 1;
        int o = (n & 1) * 16 + (lane & 15);
        float bv = sbias[dsel * 32 + o];
#pragma unroll
        for (int j = 0; j < 4; j++) {
          if (dj[j] == dsel) {
            float v = acc[nn][j] + bv;
            size_t gr = (size_t)row0 + rl0 + j;
            if (OUTMODE == 0) {
              v = fmaxf(v, 0.f);
              ((unsigned short*)outp)[gr * 64 + 32 + o] = f2bf(v);
            } else {
              ((float*)outp)[gr * 32 + o] = v;
            }
          }
        }
      }
    }
  }
}

// one wave per graph; writes mean directly
__global__ __launch_bounds__(256) void pool_seg(const float* __restrict__ h, const int* __restrict__ goff,
                                                float* __restrict__ pooled, int B) {
  int w = (int)((blockIdx.x * 256 + threadIdx.x) >> 6);
  if (w >= B) return;
  int lane = threadIdx.x & 63;
  int c = lane & 31, r2 = lane >> 5;
  int a = goff[w], b = goff[w + 1];
  float s = 0.f;
  for (int r = a + r2; r < b; r += 2) s += h[(size_t)r * 32 + c];
  s += __shfl_down(s, 32);
  if (r2 == 0) pooled[(size_t)w * 32 + c] = s / fmaxf((float)(b - a), 1.f);
}

// fc1: fused fp32->bf16 staging GEMM + colstats. BM=128, BN=256, BK=64, 512 thr.
// C[M,512] = relu(A[M,862] @ Bw[512,862]^T + bias) -> bf16; col sum/sumsq -> atomics.
__global__ __launch_bounds__(512) void gemm_fc1(const float* __restrict__ A, const float* __restrict__ Bw,
                                                const float* __restrict__ bias, unsigned short* __restrict__ Cout,
                                                float* __restrict__ csum, float* __restrict__ csq, int M, int Nn) {
  __shared__ __align__(16) unsigned short As[128 * 64];
  __shared__ __align__(16) unsigned short Bs[256 * 64];
  __shared__ float scs[256], sqs[256];
  const int tid = threadIdx.x;
  const int wid = tid >> 6, lane = tid & 63;
  const int m0 = blockIdx.y * 128, n0 = blockIdx.x * 256;
  const int wr = wid >> 2, wc = wid & 3;
  const int g4 = lane >> 4, lc = lane & 15;
  f32x4 acc[4][4] = {};

  const int arow = tid >> 2, aq = tid & 3;
  const int brow = tid >> 1, bh = tid & 1;

  for (int k0 = 0; k0 < 896; k0 += 64) {
    __syncthreads();
    // A stage: 16 cols per thread
    {
      const float* ga = A + (size_t)(m0 + arow) * MORD + k0 + aq * 16;
      int kbase = k0 + aq * 16;
      float fv[16];
      if (kbase + 16 <= MORD) {
#pragma unroll
        for (int i = 0; i < 4; i++) {
          f32x4a v = *(const f32x4a*)(ga + i * 4);
          fv[i * 4] = v[0]; fv[i * 4 + 1] = v[1]; fv[i * 4 + 2] = v[2]; fv[i * 4 + 3] = v[3];
        }
      } else {
#pragma unroll
        for (int i = 0; i < 16; i++) fv[i] = (kbase + i < MORD) ? ga[i] : 0.f;
      }
#pragma unroll
      for (int j = 0; j < 2; j++) {
        s16x8 w;
#pragma unroll
        for (int e = 0; e < 8; e++) w[e] = (short)f2bf(fv[j * 8 + e]);
        int ch = (aq * 2 + j) ^ (arow & 7);
        *(s16x8*)((char*)As + arow * 128 + ch * 16) = w;
      }
    }
    // B stage: 32 cols per thread
    {
      const float* gb = Bw + (size_t)(n0 + brow) * MORD + k0 + bh * 32;
      int kbase = k0 + bh * 32;
      float fv[32];
      if (kbase + 32 <= MORD) {
#pragma unroll
        for (int i = 0; i < 8; i++) {
          f32x4a v = *(const f32x4a*)(gb + i * 4);
          fv[i * 4] = v[0]; fv[i * 4 + 1] = v[1]; fv[i * 4 + 2] = v[2]; fv[i * 4 + 3] = v[3];
        }
      } else {
#pragma unroll
        for (int i = 0; i < 32; i++) fv[i] = (kbase + i < MORD) ? gb[i] : 0.f;
      }
#pragma unroll
      for (int j = 0; j < 4; j++) {
        s16x8 w;
#pragma unroll
        for (int e = 0; e < 8; e++) w[e] = (short)f2bf(fv[j * 8 + e]);
        int ch = (bh * 4 + j) ^ (brow & 7);
        *(s16x8*)((char*)Bs + brow * 128 + ch * 16) = w;
      }
    }
    __syncthreads();
#pragma unroll
    for (int kk = 0; kk < 2; kk++) {
      s16x8 af[4], bfr[4];
#pragma unroll
      for (int m = 0; m < 4; m++) {
        int ra = wr * 64 + m * 16 + lc;
        af[m] = *(const s16x8*)((const char*)As + ra * 128 + (((kk * 4 + g4) ^ (ra & 7)) * 16));
      }
#pragma unroll
      for (int n = 0; n < 4; n++) {
        int rb = wc * 64 + n * 16 + lc;
        bfr[n] = *(const s16x8*)((const char*)Bs + rb * 128 + (((kk * 4 + g4) ^ (rb & 7)) * 16));
      }
#pragma unroll
      for (int m = 0; m < 4; m++)
#pragma unroll
        for (int n = 0; n < 4; n++)
          acc[m][n] = __builtin_amdgcn_mfma_f32_16x16x32_bf16(af[m], bfr[n], acc[m][n], 0, 0, 0);
    }
  }
  __syncthreads();
  if (tid < 256) { scs[tid] = 0.f; sqs[tid] = 0.f; }
  __syncthreads();
  const int rbase = m0 + wr * 64 + g4 * 4;
#pragma unroll
  for (int n = 0; n < 4; n++) {
    int colb = wc * 64 + n * 16 + lc;
    float bv = bias[n0 + colb];
    float s = 0.f, q = 0.f;
#pragma unroll
    for (int m = 0; m < 4; m++) {
#pragma unroll
      for (int j = 0; j < 4; j++) {
        float v = fmaxf(acc[m][n][j] + bv, 0.f);
        Cout[(size_t)(rbase + m * 16 + j) * Nn + n0 + colb] = f2bf(v);
        s += v;
        q = fmaf(v, v, q);
      }
    }
    s += __shfl_xor(s, 16); q += __shfl_xor(q, 16);
    s += __shfl_xor(s, 32); q += __shfl_xor(q, 32);
    if (g4 == 0) { atomicAdd(&scs[colb], s); atomicAdd(&sqs[colb], q); }
  }
  __syncthreads();
  if (tid < 256) { atomicAdd(&csum[n0 + tid], scs[tid]); atomicAdd(&csq[n0 + tid], sqs[tid]); }
}

__global__ __launch_bounds__(256) void prepW2_kernel(const float* __restrict__ W2, const float* __restrict__ b2,
                                                     const float* __restrict__ a1, const float* __restrict__ h1,
                                                     unsigned short* __restrict__ W2p, float* __restrict__ b2p,
                                                     int Nn, int K) {
  int wid = threadIdx.x >> 6, lane = threadIdx.x & 63;
  int n = blockIdx.x * 4 + wid;
  if (n >= Nn) return;
  float part = 0.f;
  for (int k = lane; k < K; k += 64) {
    float w = W2[(size_t)n * K + k];
    W2p[(size_t)n * K + k] = f2bf(w * a1[k]);
    part = fmaf(w, h1[k], part);
  }
#pragma unroll
  for (int off = 32; off > 0; off >>= 1) part += __shfl_down(part, off, 64);
  if (lane == 0) b2p[n] = b2[n] + part;
}

// bf16 MFMA GEMM (fc2): C f32 = A[M,Kp]bf16 @ Bw[Nn,Kp]bf16^T + bias
template <int OUTBF16>
__global__ __launch_bounds__(256) void gemm_mfma(const unsigned short* __restrict__ A,
                                                 const unsigned short* __restrict__ Bw,
                                                 const float* __restrict__ bias,
                                                 void* __restrict__ Cout, int M, int Nn, int Kp) {
  __shared__ __align__(16) unsigned short As[128 * 64];
  __shared__ __align__(16) unsigned short Bs[128 * 64];
  int tid = threadIdx.x;
  int wid = tid >> 6, lane = tid & 63;
  int m0 = blockIdx.y * 128, n0 = blockIdx.x * 128;
  int wr = wid >> 1, wc = wid & 1;
  f32x4 acc[4][4] = {};

  int srow_l = lane >> 3;
  int scol = (lane & 7) * 8;
  int aReadBase = ((wr * 64 + (lane & 15)) * 128) + ((lane >> 4) * 16);
  int bReadBase = ((wc * 64 + (lane & 15)) * 128) + ((lane >> 4) * 16);

  const unsigned short* Ablk = A + (size_t)m0 * Kp;
  const unsigned short* Bblk = Bw + (size_t)n0 * Kp;

  for (int k0 = 0; k0 < Kp; k0 += 64) {
#pragma unroll
    for (int i = 0; i < 4; i++) {
      int s = wid * 4 + i;
      int row = s * 8 + srow_l;
      const unsigned short* ga = Ablk + (size_t)row * Kp + k0 + scol;
      const unsigned short* gb = Bblk + (size_t)row * Kp + k0 + scol;
      __builtin_amdgcn_global_load_lds((const __attribute__((address_space(1))) void*)ga,
                                       (__attribute__((address_space(3))) void*)(As + s * 512), 16, 0, 0);
      __builtin_amdgcn_global_load_lds((const __attribute__((address_space(1))) void*)gb,
                                       (__attribute__((address_space(3))) void*)(Bs + s * 512), 16, 0, 0);
    }
    __syncthreads();
#pragma unroll
    for (int kk = 0; kk < 2; kk++) {
      s16x8 af[4], bfr[4];
#pragma unroll
      for (int m = 0; m < 4; m++)
        af[m] = *(const s16x8*)((const char*)As + aReadBase + m * (16 * 128) + kk * 64);
#pragma unroll
      for (int n = 0; n < 4; n++)
        bfr[n] = *(const s16x8*)((const char*)Bs + bReadBase + n * (16 * 128) + kk * 64);
#pragma unroll
      for (int m = 0; m < 4; m++)
#pragma unroll
        for (int n = 0; n < 4; n++)
          acc[m][n] = __builtin_amdgcn_mfma_f32_16x16x32_bf16(af[m], bfr[n], acc[m][n], 0, 0, 0);
    }
    __syncthreads();
  }

  int rbase = m0 + wr * 64 + (lane >> 4) * 4;
  int cbase = n0 + wc * 64 + (lane & 15);
#pragma unroll
  for (int m = 0; m < 4; m++)
#pragma unroll
    for (int n = 0; n < 4; n++) {
      int col = cbase + n * 16;
      float bv = bias[col];
#pragma unroll
      for (int j = 0; j < 4; j++) {
        int row = rbase + m * 16 + j;
        float v = fmaxf(acc[m][n][j] + bv, 0.f);
        if (OUTBF16)
          ((unsigned short*)Cout)[(size_t)row * Nn + col] = f2bf(v);
        else
          ((float*)Cout)[(size_t)row * Nn + col] = v;
      }
    }
}

// fp32 fallback GEMM (fc3)
template <bool RELU>
__global__ __launch_bounds__(256) void gemm_bias(const float* __restrict__ A, const float* __restrict__ Bw,
                                                 const float* __restrict__ bias,
                                                 const float* __restrict__ scA, const float* __restrict__ shA,
                                                 float* __restrict__ C, int M, int Nn, int K) {
  const int BM = 64, BN = 64, BK = 16;
  __shared__ float As[BK][BM + 1];
  __shared__ float Bs[BK][BN + 1];
  int bm = blockIdx.y * BM, bn = blockIdx.x * BN;
  int tid = threadIdx.x;
  int tr = tid / 16, tc = tid % 16;
  float acc[4][4] = {};
  for (int k0 = 0; k0 < K; k0 += BK) {
    for (int i = tid; i < BM * BK; i += 256) {
      int m = i / BK, k = i % BK;
      float v = 0.f;
      if (k0 + k < K) {
        v = A[(size_t)(bm + m) * K + k0 + k];
        if (scA) v = fmaf(v, scA[k0 + k], shA[k0 + k]);
      }
      As[k][m] = v;
    }
    for (int i = tid; i < BN * BK; i += 256) {
      int n = i / BK, k = i % BK;
      float v = 0.f;
      if (k0 + k < K) v = Bw[(size_t)(bn + n) * K + k0 + k];
      Bs[k][n] = v;
    }
    __syncthreads();
#pragma unroll
    for (int k = 0; k < BK; k++) {
      float a4[4], b4[4];
#pragma unroll
      for (int xx = 0; xx < 4; xx++) a4[xx] = As[k][tr * 4 + xx];
#pragma unroll
      for (int yy = 0; yy < 4; yy++) b4[yy] = Bs[k][tc * 4 + yy];
#pragma unroll
      for (int xx = 0; xx < 4; xx++)
#pragma unroll
        for (int yy = 0; yy < 4; yy++) acc[xx][yy] = fmaf(a4[xx], b4[yy], acc[xx][yy]);
    }
    __syncthreads();
  }
  for (int xx = 0; xx < 4; xx++) {
    int m = bm + tr * 4 + xx;
    for (int yy = 0; yy < 4; yy++) {
      int n = bn + tc * 4 + yy;
      float v = acc[xx][yy] + bias[n];
      if (RELU) v = fmaxf(v, 0.f);
      C[(size_t)m * Nn + n] = v;
    }
  }
}

__global__ __launch_bounds__(256) void colstats_kernel(const float* __restrict__ X, int M, int C,
                                                       float* __restrict__ sum, float* __restrict__ sumsq) {
  int cl = threadIdx.x & 63, rl = threadIdx.x >> 6;
  int c = blockIdx.x * 64 + cl;
  float s = 0.f, q = 0.f;
  int r0 = blockIdx.y * 256;
  int rend = min(r0 + 256, M);
  for (int r = r0 + rl; r < rend; r += 4) {
    float v = X[(size_t)r * C + c];
    s += v;
    q = fmaf(v, v, q);
  }
  __shared__ float ss[4][64];
  __shared__ float qq[4][64];
  ss[rl][cl] = s;
  qq[rl][cl] = q;
  __syncthreads();
  if (rl == 0) {
    s = ss[0][cl] + ss[1][cl] + ss[2][cl] + ss[3][cl];
    q = qq[0][cl] + qq[1][cl] + qq[2][cl] + qq[3][cl];
    atomicAdd(&sum[c], s);
    atomicAdd(&sumsq[c], q);
  }
}

__global__ __launch_bounds__(256) void bn_coef_kernel(const float* __restrict__ sum, const float* __restrict__ sumsq,
                                                      const float* __restrict__ g, const float* __restrict__ be,
                                                      float* __restrict__ a, float* __restrict__ b, int C, float invM) {
  int c = blockIdx.x * blockDim.x + threadIdx.x;
  if (c >= C) return;
  float mu = sum[c] * invM;
  float var = sumsq[c] * invM - mu * mu;
  float s = g[c] * rsqrtf(var + 1e-5f);
  a[c] = s;
  b[c] = be[c] - mu * s;
}

__global__ __launch_bounds__(256) void head_kernel(const float* __restrict__ pooled,
                                                   const float* __restrict__ m3, const float* __restrict__ a3,
                                                   const float* __restrict__ b3, const float* __restrict__ Wout,
                                                   const float* __restrict__ bout, float* __restrict__ out, int B) {
  int b = blockIdx.x * blockDim.x + threadIdx.x;
  if (b >= B) return;
  float acc = bout[0];
#pragma unroll
  for (int j = 0; j < 32; j++) acc = fmaf(pooled[(size_t)b * 32 + j], Wout[j], acc);
#pragma unroll
  for (int j = 0; j < 64; j++) acc = fmaf(fmaf(m3[(size_t)b * 64 + j], a3[j], b3[j]), Wout[32 + j], acc);
  out[b] = 1.f / (1.f + expf(-acc));
}

extern "C" void kernel_launch(void* const* d_in, const int* in_sizes, int n_in,
                              void* d_out, int out_size, void* d_ws, size_t ws_size,
                              hipStream_t stream) {
  const float* x = (const float*)d_in[0];
  const int* eidx = (const int*)d_in[1];
  const int* batch = (const int*)d_in[2];
  const float* xmord = (const float*)d_in[3];
  const float* Wl1 = (const float*)d_in[4];
  const float* bl1 = (const float*)d_in[5];
  const float* Wr1 = (const float*)d_in[6];
  const float* Wl2 = (const float*)d_in[7];
  const float* bl2 = (const float*)d_in[8];
  const float* Wr2 = (const float*)d_in[9];
  const float* Wl3 = (const float*)d_in[10];
  const float* bl3 = (const float*)d_in[11];
  const float* Wr3 = (const float*)d_in[12];
  const float* Wf1 = (const float*)d_in[13];
  const float* bf1 = (const float*)d_in[14];
  const float* g1 = (const float*)d_in[15];
  const float* be1 = (const float*)d_in[16];
  const float* Wf2 = (const float*)d_in[17];
  const float* bf2 = (const float*)d_in[18];
  const float* g2 = (const float*)d_in[19];
  const float* be2 = (const float*)d_in[20];
  const float* Wf3 = (const float*)d_in[21];
  const float* bf3 = (const float*)d_in[22];
  const float* g3 = (const float*)d_in[23];
  const float* be3 = (const float*)d_in[24];
  const float* Wout = (const float*)d_in[25];
  const float* bout = (const float*)d_in[26];
  float* out = (float*)d_out;

  const int N = in_sizes[2];
  const int E = in_sizes[1] / 2;
  const int B = in_sizes[3] / MORD;
  const int nbins = (N + 1023) >> 10;
  const int* src = eidx;
  const int* dst = eidx + E;

  char* ws = (char*)d_ws;
  size_t off_ = 0;
  auto alloc = [&](size_t bytes) { size_t o = off_; off_ += (bytes + 255) & ~(size_t)255; return o; };
  size_t oHX1 = alloc((size_t)N * 64 * 2);   // hx1 [N][32]bf16 + H3 f32 [N][32] overlay
  size_t oHX2 = alloc((size_t)N * 64 * 2);   // hx2; later W2p/b2p overlay
  size_t oHX3 = alloc((size_t)N * 64 * 2);   // hx3; later m1/m2/m3 overlay
  size_t oOff = alloc((size_t)(N + 1) * 4);
  size_t oCsr = alloc((size_t)E * 4);
  size_t oEbuf = alloc((size_t)E * 8);
  size_t oGoff = alloc((size_t)(B + 1) * 4);
  size_t oPool = alloc((size_t)B * 32 * 4);
  size_t oStats = alloc(8192 * 4);           // st[0..4095] | bhist[4096..4607] | boff | gcur
  size_t oWc1 = alloc(352 * 64 * 2);
  size_t oWc2 = alloc(352 * 64 * 2);
  size_t oWc3 = alloc(352 * 64 * 2);
  (void)ws_size;

  unsigned short* hx1 = (unsigned short*)(ws + oHX1);
  unsigned short* hx2 = (unsigned short*)(ws + oHX2);
  unsigned short* hx3 = (unsigned short*)(ws + oHX3);
  float* H3 = (float*)(ws + oHX1);
  int* offp = (int*)(ws + oOff);
  int* csr = (int*)(ws + oCsr);
  unsigned long long* ebuf = (unsigned long long*)(ws + oEbuf);
  int* goff = (int*)(ws + oGoff);
  float* pooled = (float*)(ws + oPool);
  float* st = (float*)(ws + oStats);
  int* bhist = (int*)(st + 4096);
  int* boff = (int*)(st + 4608);
  int* gcur = (int*)(st + 5184);
  unsigned short* Wc1 = (unsigned short*)(ws + oWc1);
  unsigned short* Wc2 = (unsigned short*)(ws + oWc2);
  unsigned short* Wc3 = (unsigned short*)(ws + oWc3);
  float *s1 = st, *q1 = st + 512, *a1 = st + 1024, *h1 = st + 1536;
  float *s2 = st + 2048, *q2 = st + 2176, *a2 = st + 2304, *h2 = st + 2432;
  float *s3 = st + 2560, *q3 = st + 2624, *a3 = st + 2688, *h3 = st + 2752;

  unsigned short* W2p = (unsigned short*)(ws + oHX2);
  float* b2p = (float*)(ws + oHX2 + 131072);
  unsigned short* m1 = (unsigned short*)(ws + oHX3);
  float* m2 = (float*)(ws + oHX3 + 16777216);
  float* m3 = (float*)(ws + oHX3 + 25165824);

  // one memset: st (16KB) + bhist (2KB)
  hipMemsetAsync(st, 0, 4608 * 4, stream);

  // Binned CSR build
  bin_hist<<<400, 256, 0, stream>>>(dst, bhist, E, nbins);
  bin_scan<<<1, 512, 0, stream>>>(bhist, boff, gcur, nbins, E);
  bin_split<<<400, 256, 0, stream>>>(src, dst, gcur, ebuf, E, nbins);
  bin_csr<<<nbins, 256, 0, stream>>>(ebuf, boff, offp, csr, N, E);
  graph_off<<<(B + 1 + 255) / 256, 256, 0, stream>>>(batch, goff, N, B);
  prep_wcat3<<<dim3(88, 3), 256, 0, stream>>>(Wl1, Wr1, Wc1, Wl2, Wr2, Wc2, Wl3, Wr3, Wc3);

  // GNN layers
  prep_hx1<<<(N + 255) / 256, 256, 0, stream>>>(x, offp, csr, hx1, N);
  mfconv_mfma<1, 4, 0><<<512, 512, 0, stream>>>(hx1, Wc1, bl1, offp, hx2, N);
  gather_bf16<<<(int)(((long long)N * 4 + 255) / 256), 256, 0, stream>>>(hx2, offp, csr, hx2, N);
  mfconv_mfma<2, 8, 0><<<512, 512, 0, stream>>>(hx2, Wc2, bl2, offp, hx3, N);
  gather_bf16<<<(int)(((long long)N * 4 + 255) / 256), 256, 0, stream>>>(hx3, offp, csr, hx3, N);
  mfconv_mfma<2, 8, 1><<<512, 512, 0, stream>>>(hx3, Wc3, bl3, offp, H3, N);

  pool_seg<<<(B * 64 + 255) / 256, 256, 0, stream>>>(H3, goff, pooled, B);

  // ---- MLP head ----
  gemm_fc1<<<dim3(2, B / 128), 512, 0, stream>>>(xmord, Wf1, bf1, m1, s1, q1, B, 512);
  bn_coef_kernel<<<2, 256, 0, stream>>>(s1, q1, g1, be1, a1, h1, 512, 1.f / B);

  prepW2_kernel<<<32, 256, 0, stream>>>(Wf2, bf2, a1, h1, W2p, b2p, 128, 512);
  gemm_mfma<0><<<dim3(1, B / 128), 256, 0, stream>>>(m1, W2p, b2p, m2, B, 128, 512);
  colstats_kernel<<<dim3(2, B / 256), 256, 0, stream>>>(m2, B, 128, s2, q2);
  bn_coef_kernel<<<1, 256, 0, stream>>>(s2, q2, g2, be2, a2, h2, 128, 1.f / B);

  gemm_bias<true><<<dim3(1, B / 64), 256, 0, stream>>>(m2, Wf3, bf3, a2, h2, m3, B, 64, 128);
  colstats_kernel<<<dim3(1, B / 256), 256, 0, stream>>>(m3, B, 64, s3, q3);
  bn_coef_kernel<<<1, 256, 0, stream>>>(s3, q3, g3, be3, a3, h3, 64, 1.f / B);

  head_kernel<<<(B + 255) / 256, 256, 0, stream>>>(pooled, m3, a3, h3, Wout, bout, out, B);
}